// Round 5
// baseline (424.037 us; speedup 1.0000x reference)
//
#include <hip/hip_runtime.h>
#include <hip/hip_bf16.h>
#include <math.h>

#define D_   1024
#define H_   16
#define HD_  64
#define S_   2048
#define B_   2
#define FF_  4096
#define M_   (B_*S_)      // 4096 rows
#define QKVN (3*D_)       // 3072

typedef __bf16 bf16;
typedef bf16 bf16x8 __attribute__((ext_vector_type(8)));
typedef bf16 bf16x4 __attribute__((ext_vector_type(4)));
typedef float f32x4 __attribute__((ext_vector_type(4)));

#define MFMA16(a,b,c) __builtin_amdgcn_mfma_f32_16x16x32_bf16(a,b,c,0,0,0)

// async global->LDS 16B per lane (wave-uniform LDS base + lane*16)
__device__ __forceinline__ void gld16(const void* g, void* l) {
    __builtin_amdgcn_global_load_lds(
        (const __attribute__((address_space(1))) void*)g,
        (__attribute__((address_space(3))) void*)l, 16, 0, 0);
}

// ---------------- weight transpose + cast: W[K][N] f32 -> WT[N][K] bf16 ----------------
__global__ __launch_bounds__(256) void transpose_cast(const float* __restrict__ W,
                                                      bf16* __restrict__ WT,
                                                      int K, int N) {
    __shared__ float t[64][65];
    int k0 = blockIdx.x * 64, n0 = blockIdx.y * 64;
    int tid = threadIdx.x;
    #pragma unroll
    for (int i = 0; i < 16; i++) {
        int e = tid + i * 256; int r = e >> 6, c = e & 63;
        t[r][c] = W[(size_t)(k0 + r) * N + n0 + c];
    }
    __syncthreads();
    #pragma unroll
    for (int i = 0; i < 16; i++) {
        int e = tid + i * 256; int r = e >> 6, c = e & 63;
        WT[(size_t)(n0 + r) * K + k0 + c] = (bf16)t[c][r];
    }
}

// ---------------- transpose V section of qkv into VT[bh][d][s] ----------------
__global__ __launch_bounds__(256) void transpose_v(const bf16* __restrict__ qkv,
                                                   bf16* __restrict__ VT) {
    __shared__ __align__(16) bf16 t[64][72];
    int bh = blockIdx.y; int b = bh >> 4, h = bh & 15;
    int s0 = blockIdx.x * 64;
    const bf16* vbase = qkv + (size_t)b * S_ * QKVN + 2048 + h * 64;
    int tid = threadIdx.x;
    #pragma unroll
    for (int i = 0; i < 2; i++) {
        int e = tid + i * 256; int r = e >> 3, cg = e & 7;
        *(bf16x8*)&t[r][cg * 8] = *(const bf16x8*)&vbase[(size_t)(s0 + r) * QKVN + cg * 8];
    }
    __syncthreads();
    #pragma unroll
    for (int i = 0; i < 2; i++) {
        int e = tid + i * 256; int d = e >> 3, cg = e & 7;
        bf16x8 v;
        #pragma unroll
        for (int j = 0; j < 8; j++) v[j] = t[cg * 8 + j][d];
        *(bf16x8*)&VT[((size_t)bh * 64 + d) * S_ + s0 + cg * 8] = v;
    }
}

// ---------------- concat q,k,v biases into one [3072] buffer ----------------
__global__ void concat3(const float* __restrict__ a, const float* __restrict__ b,
                        const float* __restrict__ c, float* __restrict__ o) {
    int i = blockIdx.x * 256 + threadIdx.x;
    o[i] = (i < 1024) ? a[i] : (i < 2048 ? b[i - 1024] : c[i - 2048]);
}

// ---------------- layernorm (ddof=1, eps on std) f32 in -> bf16 out ----------------
__global__ __launch_bounds__(256) void ln_kernel(const float* __restrict__ x,
                                                 const float* __restrict__ g,
                                                 const float* __restrict__ sh,
                                                 bf16* __restrict__ out) {
    int row = blockIdx.x * 4 + (threadIdx.x >> 6);
    int lane = threadIdx.x & 63;
    const float4* xr = (const float4*)(x + (size_t)row * D_);
    float4 v[4]; float sum = 0.f, ss = 0.f;
    #pragma unroll
    for (int c = 0; c < 4; c++) {
        v[c] = xr[lane + 64 * c];
        sum += v[c].x + v[c].y + v[c].z + v[c].w;
        ss  += v[c].x * v[c].x + v[c].y * v[c].y + v[c].z * v[c].z + v[c].w * v[c].w;
    }
    #pragma unroll
    for (int o = 32; o; o >>= 1) { sum += __shfl_xor(sum, o); ss += __shfl_xor(ss, o); }
    float mean = sum * (1.f / 1024.f);
    float var  = (ss - 1024.f * mean * mean) * (1.f / 1023.f);
    float inv  = 1.f / (sqrtf(var) + 1e-5f);
    const float4* gp = (const float4*)g;
    const float4* sp = (const float4*)sh;
    bf16x4* op = (bf16x4*)(out + (size_t)row * D_);
    #pragma unroll
    for (int c = 0; c < 4; c++) {
        int idx = lane + 64 * c;
        float4 gv = gp[idx], sv = sp[idx];
        float y0 = (v[c].x - mean) * inv * gv.x + sv.x;
        float y1 = (v[c].y - mean) * inv * gv.y + sv.y;
        float y2 = (v[c].z - mean) * inv * gv.z + sv.z;
        float y3 = (v[c].w - mean) * inv * gv.w + sv.w;
        op[idx] = (bf16x4){(bf16)y0, (bf16)y1, (bf16)y2, (bf16)y3};
    }
}

// ================= 256x256 BK=32 8-wave triple-buffered counted-vmcnt GEMM =================
// (unchanged from round 4 — see comments there)
template<int MODE>
__global__ __launch_bounds__(512, 2) void gemm256(const bf16* __restrict__ A,
                                                  const bf16* __restrict__ BT,
                                                  const float* __restrict__ bias,
                                                  void* __restrict__ outp,
                                                  int M, int N, int K, int KSLICE) {
    __shared__ __align__(16) bf16 a_lds[3 * 256 * 32];
    __shared__ __align__(16) bf16 b_lds[3 * 256 * 32];
    int tid = threadIdx.x, w = tid >> 6, lane = tid & 63;
    int gx = gridDim.x, gxy = gx * gridDim.y;
    int nwg = gxy * gridDim.z;
    int flat = blockIdx.z * gxy + blockIdx.y * gx + blockIdx.x;
    int chunk = nwg >> 3;
    int swz = (flat & 7) * chunk + (flat >> 3);
    int z = swz / gxy, rem = swz - z * gxy;
    int m0 = (rem / gx) * 256, n0 = (rem % gx) * 256;
    int kbase = z * KSLICE;
    int nk = KSLICE >> 5;
    int lr = lane & 15, lh = lane >> 4;
    int wr = w >> 2, wc = w & 3;

    int g0 = w * 64 + lane;
    int row0 = g0 >> 2, cs0 = (g0 & 3) ^ ((row0 >> 1) & 3);
    int g1 = g0 + 512;
    int row1 = g1 >> 2, cs1 = (g1 & 3) ^ ((row1 >> 1) & 3);
    int dst0 = w * 512;
    int dst1 = w * 512 + 4096;

    auto STAGE = [&](int buf, int k0) {
        bf16* ab = a_lds + buf * 8192;
        bf16* bb = b_lds + buf * 8192;
        gld16(&A [(size_t)(m0 + row0) * K + k0 + cs0 * 8], ab + dst0);
        gld16(&A [(size_t)(m0 + row1) * K + k0 + cs1 * 8], ab + dst1);
        gld16(&BT[(size_t)(n0 + row0) * K + k0 + cs0 * 8], bb + dst0);
        gld16(&BT[(size_t)(n0 + row1) * K + k0 + cs1 * 8], bb + dst1);
    };

    f32x4 acc[8][4] = {};
    STAGE(0, kbase);
    STAGE(1, kbase + 32);
    asm volatile("s_waitcnt vmcnt(4)" ::: "memory");
    __builtin_amdgcn_s_barrier();
    __builtin_amdgcn_sched_barrier(0);

    int rchk = (lr >> 1) & 3;
    int fcol = ((lh ^ rchk) * 8);
    for (int kt = 0; kt < nk; ++kt) {
        int b0 = kt % 3;
        const bf16* ab = a_lds + b0 * 8192;
        const bf16* bb = b_lds + b0 * 8192;
        bf16x8 af[8], bf[4];
        #pragma unroll
        for (int m = 0; m < 8; m++)
            af[m] = *(const bf16x8*)&ab[(wr * 128 + m * 16 + lr) * 32 + fcol];
        #pragma unroll
        for (int n = 0; n < 4; n++)
            bf[n] = *(const bf16x8*)&bb[(wc * 64 + n * 16 + lr) * 32 + fcol];
        if (kt + 2 < nk) {
            STAGE((kt + 2) % 3, kbase + (kt + 2) * 32);
            asm volatile("s_waitcnt vmcnt(4)" ::: "memory");
        } else {
            asm volatile("s_waitcnt vmcnt(0)" ::: "memory");
        }
        __builtin_amdgcn_s_setprio(1);
        #pragma unroll
        for (int m = 0; m < 8; m++)
            #pragma unroll
            for (int n = 0; n < 4; n++)
                acc[m][n] = MFMA16(af[m], bf[n], acc[m][n]);
        __builtin_amdgcn_s_setprio(0);
        __builtin_amdgcn_s_barrier();
        __builtin_amdgcn_sched_barrier(0);
    }

    #pragma unroll
    for (int m = 0; m < 8; m++) {
        #pragma unroll
        for (int n = 0; n < 4; n++) {
            int col = n0 + wc * 64 + n * 16 + lr;
            float bv = (MODE == 3) ? 0.f : bias[col];
            #pragma unroll
            for (int r = 0; r < 4; r++) {
                int row = m0 + wr * 128 + m * 16 + lh * 4 + r;
                float vv = acc[m][n][r] + bv;
                if (MODE == 2) vv = 0.5f * vv * (1.f + erff(vv * 0.70710678118654752f));
                if (MODE == 3) ((float*)outp)[((size_t)z * M + row) * N + col] = vv;
                else           ((bf16*)outp)[(size_t)row * N + col] = (bf16)vv;
            }
        }
    }
}

// ---------------- split-K reduce: out = sum_z part[z] + bias + res (f32, N=1024) ----------------
__global__ __launch_bounds__(256) void reduce4(const float* __restrict__ part,
                                               const float* __restrict__ bias,
                                               const float* __restrict__ res,
                                               float* __restrict__ out) {
    int i = blockIdx.x * 256 + threadIdx.x;
    const float4* p = (const float4*)part;
    const size_t s4 = (size_t)M_ * 1024 / 4;
    float4 a = p[i], b = p[i + s4], c = p[i + 2 * s4], d = p[i + 3 * s4];
    float4 bv = ((const float4*)bias)[i & 255];
    float4 rv = ((const float4*)res)[i];
    float4 o;
    o.x = a.x + b.x + c.x + d.x + bv.x + rv.x;
    o.y = a.y + b.y + c.y + d.y + bv.y + rv.y;
    o.z = a.z + b.z + c.z + d.z + bv.z + rv.z;
    o.w = a.w + b.w + c.w + d.w + bv.w + rv.w;
    ((float4*)out)[i] = o;
}

// ------- fused split-K reduce + LayerNorm: x2 = sum_z part + bias + res; h2 = LN(x2) -------
// one block per row (256 threads x float4 = 1024 elems)
__global__ __launch_bounds__(256) void reduce_ln(const float* __restrict__ part,
                                                 const float* __restrict__ bias,
                                                 const float* __restrict__ res,
                                                 const float* __restrict__ g,
                                                 const float* __restrict__ sh,
                                                 float* __restrict__ x2,
                                                 bf16* __restrict__ h2) {
    __shared__ float s_sum[4], s_ss[4];
    int row = blockIdx.x, t = threadIdx.x;
    int wv = t >> 6, lane = t & 63;
    size_t i = (size_t)row * 256 + t;
    const float4* p = (const float4*)part;
    const size_t s4 = (size_t)M_ * 1024 / 4;
    float4 a = p[i], b = p[i + s4], c = p[i + 2 * s4], d = p[i + 3 * s4];
    float4 bv = ((const float4*)bias)[t];
    float4 rv = ((const float4*)res)[i];
    float4 v;
    v.x = a.x + b.x + c.x + d.x + bv.x + rv.x;
    v.y = a.y + b.y + c.y + d.y + bv.y + rv.y;
    v.z = a.z + b.z + c.z + d.z + bv.z + rv.z;
    v.w = a.w + b.w + c.w + d.w + bv.w + rv.w;
    ((float4*)x2)[i] = v;
    float sum = v.x + v.y + v.z + v.w;
    float ss  = v.x * v.x + v.y * v.y + v.z * v.z + v.w * v.w;
    #pragma unroll
    for (int o = 32; o; o >>= 1) { sum += __shfl_xor(sum, o); ss += __shfl_xor(ss, o); }
    if (lane == 0) { s_sum[wv] = sum; s_ss[wv] = ss; }
    __syncthreads();
    sum = s_sum[0] + s_sum[1] + s_sum[2] + s_sum[3];
    ss  = s_ss[0] + s_ss[1] + s_ss[2] + s_ss[3];
    float mean = sum * (1.f / 1024.f);
    float var  = (ss - 1024.f * mean * mean) * (1.f / 1023.f);
    float inv  = 1.f / (sqrtf(var) + 1e-5f);
    float4 gv = ((const float4*)g)[t], sv = ((const float4*)sh)[t];
    bf16x4 o4;
    o4[0] = (bf16)((v.x - mean) * inv * gv.x + sv.x);
    o4[1] = (bf16)((v.y - mean) * inv * gv.y + sv.y);
    o4[2] = (bf16)((v.z - mean) * inv * gv.z + sv.z);
    o4[3] = (bf16)((v.w - mean) * inv * gv.w + sv.w);
    *(bf16x4*)&h2[(size_t)row * D_ + t * 4] = o4;
}

// ---------------- causal flash attention v3: QBLK=128 (4 waves x 32 q), KVBLK=64 ----------------
// grid: (B*H, S/128), q-tiles reversed (heavy first). T14 async staging: next tile's K/V loads
// issue before compute, ds_write consumes them next iteration.
__global__ __launch_bounds__(256) void attn_kernel(const bf16* __restrict__ qkv,
                                                   const bf16* __restrict__ VT,
                                                   bf16* __restrict__ ctx) {
    __shared__ __align__(16) bf16 k_lds[64 * 72];
    __shared__ __align__(16) bf16 vt_lds[64 * 72];
    __shared__ __align__(16) bf16 p_lds[4 * 32 * 72];
    int bh = blockIdx.x; int b = bh >> 4, h = bh & 15;
    int qt = gridDim.y - 1 - blockIdx.y;
    int q0 = qt * 128;
    int tid = threadIdx.x, w = tid >> 6, lane = tid & 63;
    int lr = lane & 15, lh = lane >> 4;
    const size_t RS = QKVN;
    const bf16* qbase = qkv + (size_t)b * S_ * RS + h * 64;
    const bf16* kbase = qbase + 1024;
    const bf16* vtb = VT + (size_t)bh * 64 * S_;

    // Q fragments for 2 row-frags x 2 d-chunks, pre-scaled by 1/8 (power of 2 -> exact)
    bf16x8 aq[2][2];
    #pragma unroll
    for (int rf = 0; rf < 2; rf++) {
        int qrow = q0 + w * 32 + rf * 16 + lr;
        #pragma unroll
        for (int dc = 0; dc < 2; dc++) {
            bf16x8 t8 = *(const bf16x8*)&qbase[(size_t)qrow * RS + dc * 32 + lh * 8];
            #pragma unroll
            for (int j = 0; j < 8; j++) t8[j] = (bf16)((float)t8[j] * 0.125f);
            aq[rf][dc] = t8;
        }
    }

    f32x4 o_acc[2][4] = {};
    float mrow[2][4], lrow[2][4];
    #pragma unroll
    for (int rf = 0; rf < 2; rf++)
        #pragma unroll
        for (int r = 0; r < 4; r++) { mrow[rf][r] = -1e30f; lrow[rf][r] = 0.f; }

    int er = tid >> 3, ecg = tid & 7;   // 32 rows x 8 col-granules, 2 passes
    int ntile = 2 * qt + 2;
    // prologue: loads for tile 0
    bf16x8 kreg0 = *(const bf16x8*)&kbase[(size_t)er * RS + ecg * 8];
    bf16x8 kreg1 = *(const bf16x8*)&kbase[(size_t)(er + 32) * RS + ecg * 8];
    bf16x8 vreg0 = *(const bf16x8*)&vtb[(size_t)er * S_ + ecg * 8];
    bf16x8 vreg1 = *(const bf16x8*)&vtb[(size_t)(er + 32) * S_ + ecg * 8];

    for (int t = 0; t < ntile; t++) {
        int kv0 = t * 64;
        // write staged regs into LDS (compiler inserts vmcnt wait on the loads)
        *(bf16x8*)&k_lds [er * 72 + ecg * 8]        = kreg0;
        *(bf16x8*)&k_lds [(er + 32) * 72 + ecg * 8] = kreg1;
        *(bf16x8*)&vt_lds[er * 72 + ecg * 8]        = vreg0;
        *(bf16x8*)&vt_lds[(er + 32) * 72 + ecg * 8] = vreg1;
        __syncthreads();
        if (t + 1 < ntile) {    // T14: issue next tile's loads now; consumed next iteration
            int kn = kv0 + 64;
            kreg0 = *(const bf16x8*)&kbase[(size_t)(kn + er) * RS + ecg * 8];
            kreg1 = *(const bf16x8*)&kbase[(size_t)(kn + er + 32) * RS + ecg * 8];
            vreg0 = *(const bf16x8*)&vtb[(size_t)er * S_ + kn + ecg * 8];
            vreg1 = *(const bf16x8*)&vtb[(size_t)(er + 32) * S_ + kn + ecg * 8];
        }

        // QK^T: 2 row-frags x 4 kv-frags x 2 d-chunks
        f32x4 sc[2][4] = {};
        #pragma unroll
        for (int kf = 0; kf < 4; kf++)
            #pragma unroll
            for (int dc = 0; dc < 2; dc++) {
                bf16x8 bk = *(const bf16x8*)&k_lds[(kf * 16 + lr) * 72 + dc * 32 + lh * 8];
                sc[0][kf] = MFMA16(aq[0][dc], bk, sc[0][kf]);
                sc[1][kf] = MFMA16(aq[1][dc], bk, sc[1][kf]);
            }

        // causal mask only on the two diagonal tiles
        if (t >= ntile - 2) {
            #pragma unroll
            for (int kf = 0; kf < 4; kf++) {
                int kvg = kv0 + kf * 16 + lr;
                #pragma unroll
                for (int rf = 0; rf < 2; rf++)
                    #pragma unroll
                    for (int r = 0; r < 4; r++) {
                        int qg = q0 + w * 32 + rf * 16 + lh * 4 + r;
                        if (kvg > qg) sc[rf][kf][r] = -100000.0f;
                    }
            }
        }

        // row max over kv: in-thread across kf, then 16-lane butterfly
        float pmax[2][4];
        #pragma unroll
        for (int rf = 0; rf < 2; rf++)
            #pragma unroll
            for (int r = 0; r < 4; r++)
                pmax[rf][r] = fmaxf(fmaxf(sc[rf][0][r], sc[rf][1][r]),
                                    fmaxf(sc[rf][2][r], sc[rf][3][r]));
        #pragma unroll
        for (int o = 1; o < 16; o <<= 1)
            #pragma unroll
            for (int rf = 0; rf < 2; rf++)
                #pragma unroll
                for (int r = 0; r < 4; r++)
                    pmax[rf][r] = fmaxf(pmax[rf][r], __shfl_xor(pmax[rf][r], o));

        float scl[2][4], psum[2][4];
        #pragma unroll
        for (int rf = 0; rf < 2; rf++)
            #pragma unroll
            for (int r = 0; r < 4; r++) {
                float mn = fmaxf(mrow[rf][r], pmax[rf][r]);
                scl[rf][r] = __expf(mrow[rf][r] - mn);
                mrow[rf][r] = mn;
                psum[rf][r] = 0.f;
            }
        #pragma unroll
        for (int kf = 0; kf < 4; kf++)
            #pragma unroll
            for (int rf = 0; rf < 2; rf++)
                #pragma unroll
                for (int r = 0; r < 4; r++) {
                    float p = __expf(sc[rf][kf][r] - mrow[rf][r]);
                    sc[rf][kf][r] = p;
                    psum[rf][r] += p;
                }
        #pragma unroll
        for (int o = 1; o < 16; o <<= 1)
            #pragma unroll
            for (int rf = 0; rf < 2; rf++)
                #pragma unroll
                for (int r = 0; r < 4; r++)
                    psum[rf][r] += __shfl_xor(psum[rf][r], o);
        #pragma unroll
        for (int rf = 0; rf < 2; rf++)
            #pragma unroll
            for (int r = 0; r < 4; r++)
                lrow[rf][r] = lrow[rf][r] * scl[rf][r] + psum[rf][r];
        #pragma unroll
        for (int rf = 0; rf < 2; rf++)
            #pragma unroll
            for (int df = 0; df < 4; df++)
                #pragma unroll
                for (int r = 0; r < 4; r++)
                    o_acc[rf][df][r] *= scl[rf][r];

        // P (C-layout) -> per-wave LDS -> A-layout fragments
        bf16* pw = &p_lds[w * 32 * 72];
        #pragma unroll
        for (int rf = 0; rf < 2; rf++)
            #pragma unroll
            for (int kf = 0; kf < 4; kf++)
                #pragma unroll
                for (int r = 0; r < 4; r++)
                    pw[(rf * 16 + lh * 4 + r) * 72 + kf * 16 + lr] = (bf16)sc[rf][kf][r];
        asm volatile("s_waitcnt lgkmcnt(0)" ::: "memory");
        __builtin_amdgcn_sched_barrier(0);
        bf16x8 ap[2][2];
        #pragma unroll
        for (int rf = 0; rf < 2; rf++) {
            ap[rf][0] = *(const bf16x8*)&pw[(rf * 16 + lr) * 72 + lh * 8];
            ap[rf][1] = *(const bf16x8*)&pw[(rf * 16 + lr) * 72 + 32 + lh * 8];
        }
        #pragma unroll
        for (int df = 0; df < 4; df++)
            #pragma unroll
            for (int kc = 0; kc < 2; kc++) {
                bf16x8 bv = *(const bf16x8*)&vt_lds[(df * 16 + lr) * 72 + kc * 32 + lh * 8];
                o_acc[0][df] = MFMA16(ap[0][kc], bv, o_acc[0][df]);
                o_acc[1][df] = MFMA16(ap[1][kc], bv, o_acc[1][df]);
            }
        __syncthreads();
    }

    #pragma unroll
    for (int rf = 0; rf < 2; rf++)
        #pragma unroll
        for (int df = 0; df < 4; df++)
            #pragma unroll
            for (int r = 0; r < 4; r++) {
                int row = q0 + w * 32 + rf * 16 + lh * 4 + r;
                int col = h * 64 + df * 16 + lr;
                ctx[((size_t)b * S_ + row) * D_ + col] = (bf16)(o_acc[rf][df][r] / lrow[rf][r]);
            }
}

extern "C" void kernel_launch(void* const* d_in, const int* in_sizes, int n_in,
                              void* d_out, int out_size, void* d_ws, size_t ws_size,
                              hipStream_t stream) {
    const float* x  = (const float*)d_in[0];
    const float* Wq = (const float*)d_in[1];
    const float* bq = (const float*)d_in[2];
    const float* Wk = (const float*)d_in[3];
    const float* bk = (const float*)d_in[4];
    const float* Wv = (const float*)d_in[5];
    const float* bv = (const float*)d_in[6];
    const float* Wo = (const float*)d_in[7];
    const float* bo = (const float*)d_in[8];
    const float* W1 = (const float*)d_in[9];
    const float* b1 = (const float*)d_in[10];
    const float* W2 = (const float*)d_in[11];
    const float* b2 = (const float*)d_in[12];
    const float* g1 = (const float*)d_in[13];
    const float* s1 = (const float*)d_in[14];
    const float* g2 = (const float*)d_in[15];
    const float* s2 = (const float*)d_in[16];
    float* out = (float*)d_out;

    char* ws = (char*)d_ws;
    size_t off = 0;
    auto alloc = [&](size_t bytes) -> char* {
        char* p = ws + off; off += (bytes + 255) & ~(size_t)255; return p;
    };
    bf16*  wt_qkv = (bf16*)alloc((size_t)QKVN * D_ * 2);
    bf16*  wt_o   = (bf16*)alloc((size_t)D_ * D_ * 2);
    bf16*  wt_1   = (bf16*)alloc((size_t)FF_ * D_ * 2);
    bf16*  wt_2   = (bf16*)alloc((size_t)D_ * FF_ * 2);
    float* qkvb   = (float*)alloc((size_t)QKVN * 4);
    bf16*  h1     = (bf16*)alloc((size_t)M_ * D_ * 2);
    bf16*  qkv    = (bf16*)alloc((size_t)M_ * QKVN * 2);
    bf16*  vtbuf  = (bf16*)alloc((size_t)M_ * D_ * 2);
    bf16*  ctx    = (bf16*)alloc((size_t)M_ * D_ * 2);
    float* x2     = (float*)alloc((size_t)M_ * D_ * 4);
    bf16*  h2     = (bf16*)alloc((size_t)M_ * D_ * 2);
    bf16*  gbuf   = (bf16*)alloc((size_t)M_ * FF_ * 2);
    float* part   = (float*)alloc((size_t)4 * M_ * D_ * 4);   // split-K partials (shared)

    // weight prep
    transpose_cast<<<dim3(16, 16), 256, 0, stream>>>(Wq, wt_qkv, D_, D_);
    transpose_cast<<<dim3(16, 16), 256, 0, stream>>>(Wk, wt_qkv + (size_t)D_ * D_, D_, D_);
    transpose_cast<<<dim3(16, 16), 256, 0, stream>>>(Wv, wt_qkv + (size_t)2 * D_ * D_, D_, D_);
    transpose_cast<<<dim3(16, 16), 256, 0, stream>>>(Wo, wt_o, D_, D_);
    transpose_cast<<<dim3(16, 64), 256, 0, stream>>>(W1, wt_1, D_, FF_);
    transpose_cast<<<dim3(64, 16), 256, 0, stream>>>(W2, wt_2, FF_, D_);
    concat3<<<12, 256, 0, stream>>>(bq, bk, bv, qkvb);

    // block
    ln_kernel<<<M_ / 4, 256, 0, stream>>>(x, g1, s1, h1);
    gemm256<0><<<dim3(QKVN / 256, M_ / 256, 1), 512, 0, stream>>>(h1, wt_qkv, qkvb, qkv, M_, QKVN, D_, D_);
    transpose_v<<<dim3(S_ / 64, B_ * H_), 256, 0, stream>>>(qkv, vtbuf);
    attn_kernel<<<dim3(B_ * H_, S_ / 128), 256, 0, stream>>>(qkv, vtbuf, ctx);
    gemm256<3><<<dim3(D_ / 256, M_ / 256, 4), 512, 0, stream>>>(ctx, wt_o, nullptr, part, M_, D_, D_, D_ / 4);
    reduce_ln<<<M_, 256, 0, stream>>>(part, bo, x, g2, s2, x2, h2);
    gemm256<2><<<dim3(FF_ / 256, M_ / 256, 1), 512, 0, stream>>>(h2, wt_1, b1, gbuf, M_, FF_, D_, D_);
    gemm256<3><<<dim3(D_ / 256, M_ / 256, 4), 512, 0, stream>>>(gbuf, wt_2, nullptr, part, M_, D_, FF_, FF_ / 4);
    reduce4<<<(M_ * D_) / 1024, 256, 0, stream>>>(part, b2, x2, out);
}

// Round 6
// 387.262 us; speedup vs baseline: 1.0950x; 1.0950x over previous
//
#include <hip/hip_runtime.h>
#include <hip/hip_bf16.h>
#include <math.h>

#define D_   1024
#define H_   16
#define HD_  64
#define S_   2048
#define B_   2
#define FF_  4096
#define M_   (B_*S_)      // 4096 rows
#define QKVN (3*D_)       // 3072

typedef __bf16 bf16;
typedef bf16 bf16x8 __attribute__((ext_vector_type(8)));
typedef bf16 bf16x4 __attribute__((ext_vector_type(4)));
typedef float f32x4 __attribute__((ext_vector_type(4)));

#define MFMA16(a,b,c) __builtin_amdgcn_mfma_f32_16x16x32_bf16(a,b,c,0,0,0)

// async global->LDS 16B per lane (wave-uniform LDS base + lane*16)
__device__ __forceinline__ void gld16(const void* g, void* l) {
    __builtin_amdgcn_global_load_lds(
        (const __attribute__((address_space(1))) void*)g,
        (__attribute__((address_space(3))) void*)l, 16, 0, 0);
}

// ---------------- weight transpose + cast: W[K][N] f32 -> WT[N][K] bf16 (float4 loads) ----------------
__global__ __launch_bounds__(256) void transpose_cast(const float* __restrict__ W,
                                                      bf16* __restrict__ WT,
                                                      int K, int N) {
    __shared__ float t[64][65];
    int k0 = blockIdx.x * 64, n0 = blockIdx.y * 64;
    int tid = threadIdx.x;
    int tr = tid >> 4, tc = tid & 15;
    #pragma unroll
    for (int i = 0; i < 4; i++) {
        int r = tr + i * 16;
        float4 v = *(const float4*)&W[(size_t)(k0 + r) * N + n0 + tc * 4];
        t[r][tc * 4 + 0] = v.x; t[r][tc * 4 + 1] = v.y;
        t[r][tc * 4 + 2] = v.z; t[r][tc * 4 + 3] = v.w;
    }
    __syncthreads();
    #pragma unroll
    for (int i = 0; i < 4; i++) {
        int r = tr + i * 16;
        bf16x4 o;
        #pragma unroll
        for (int j = 0; j < 4; j++) o[j] = (bf16)t[tc * 4 + j][r];
        *(bf16x4*)&WT[(size_t)(n0 + r) * K + k0 + tc * 4] = o;
    }
}

// ---------------- transpose V section of qkv into VT[bh][d][s] ----------------
__global__ __launch_bounds__(256) void transpose_v(const bf16* __restrict__ qkv,
                                                   bf16* __restrict__ VT) {
    __shared__ __align__(16) bf16 t[64][72];
    int bh = blockIdx.y; int b = bh >> 4, h = bh & 15;
    int s0 = blockIdx.x * 64;
    const bf16* vbase = qkv + (size_t)b * S_ * QKVN + 2048 + h * 64;
    int tid = threadIdx.x;
    #pragma unroll
    for (int i = 0; i < 2; i++) {
        int e = tid + i * 256; int r = e >> 3, cg = e & 7;
        *(bf16x8*)&t[r][cg * 8] = *(const bf16x8*)&vbase[(size_t)(s0 + r) * QKVN + cg * 8];
    }
    __syncthreads();
    #pragma unroll
    for (int i = 0; i < 2; i++) {
        int e = tid + i * 256; int d = e >> 3, cg = e & 7;
        bf16x8 v;
        #pragma unroll
        for (int j = 0; j < 8; j++) v[j] = t[cg * 8 + j][d];
        *(bf16x8*)&VT[((size_t)bh * 64 + d) * S_ + s0 + cg * 8] = v;
    }
}

// ---------------- concat q,k,v biases into one [3072] buffer ----------------
__global__ void concat3(const float* __restrict__ a, const float* __restrict__ b,
                        const float* __restrict__ c, float* __restrict__ o) {
    int i = blockIdx.x * 256 + threadIdx.x;
    o[i] = (i < 1024) ? a[i] : (i < 2048 ? b[i - 1024] : c[i - 2048]);
}

// ---------------- layernorm (ddof=1, eps on std) f32 in -> bf16 out ----------------
__global__ __launch_bounds__(256) void ln_kernel(const float* __restrict__ x,
                                                 const float* __restrict__ g,
                                                 const float* __restrict__ sh,
                                                 bf16* __restrict__ out) {
    int row = blockIdx.x * 4 + (threadIdx.x >> 6);
    int lane = threadIdx.x & 63;
    const float4* xr = (const float4*)(x + (size_t)row * D_);
    float4 v[4]; float sum = 0.f, ss = 0.f;
    #pragma unroll
    for (int c = 0; c < 4; c++) {
        v[c] = xr[lane + 64 * c];
        sum += v[c].x + v[c].y + v[c].z + v[c].w;
        ss  += v[c].x * v[c].x + v[c].y * v[c].y + v[c].z * v[c].z + v[c].w * v[c].w;
    }
    #pragma unroll
    for (int o = 32; o; o >>= 1) { sum += __shfl_xor(sum, o); ss += __shfl_xor(ss, o); }
    float mean = sum * (1.f / 1024.f);
    float var  = (ss - 1024.f * mean * mean) * (1.f / 1023.f);
    float inv  = 1.f / (sqrtf(var) + 1e-5f);
    const float4* gp = (const float4*)g;
    const float4* sp = (const float4*)sh;
    bf16x4* op = (bf16x4*)(out + (size_t)row * D_);
    #pragma unroll
    for (int c = 0; c < 4; c++) {
        int idx = lane + 64 * c;
        float4 gv = gp[idx], sv = sp[idx];
        float y0 = (v[c].x - mean) * inv * gv.x + sv.x;
        float y1 = (v[c].y - mean) * inv * gv.y + sv.y;
        float y2 = (v[c].z - mean) * inv * gv.z + sv.z;
        float y3 = (v[c].w - mean) * inv * gv.w + sv.w;
        op[idx] = (bf16x4){(bf16)y0, (bf16)y1, (bf16)y2, (bf16)y3};
    }
}

// ================= 256x256 BK=32 8-wave triple-buffered counted-vmcnt GEMM =================
// (unchanged from round 4 — see comments there)
template<int MODE>
__global__ __launch_bounds__(512, 2) void gemm256(const bf16* __restrict__ A,
                                                  const bf16* __restrict__ BT,
                                                  const float* __restrict__ bias,
                                                  void* __restrict__ outp,
                                                  int M, int N, int K, int KSLICE) {
    __shared__ __align__(16) bf16 a_lds[3 * 256 * 32];
    __shared__ __align__(16) bf16 b_lds[3 * 256 * 32];
    int tid = threadIdx.x, w = tid >> 6, lane = tid & 63;
    int gx = gridDim.x, gxy = gx * gridDim.y;
    int nwg = gxy * gridDim.z;
    int flat = blockIdx.z * gxy + blockIdx.y * gx + blockIdx.x;
    int chunk = nwg >> 3;
    int swz = (flat & 7) * chunk + (flat >> 3);
    int z = swz / gxy, rem = swz - z * gxy;
    int m0 = (rem / gx) * 256, n0 = (rem % gx) * 256;
    int kbase = z * KSLICE;
    int nk = KSLICE >> 5;
    int lr = lane & 15, lh = lane >> 4;
    int wr = w >> 2, wc = w & 3;

    int g0 = w * 64 + lane;
    int row0 = g0 >> 2, cs0 = (g0 & 3) ^ ((row0 >> 1) & 3);
    int g1 = g0 + 512;
    int row1 = g1 >> 2, cs1 = (g1 & 3) ^ ((row1 >> 1) & 3);
    int dst0 = w * 512;
    int dst1 = w * 512 + 4096;

    auto STAGE = [&](int buf, int k0) {
        bf16* ab = a_lds + buf * 8192;
        bf16* bb = b_lds + buf * 8192;
        gld16(&A [(size_t)(m0 + row0) * K + k0 + cs0 * 8], ab + dst0);
        gld16(&A [(size_t)(m0 + row1) * K + k0 + cs1 * 8], ab + dst1);
        gld16(&BT[(size_t)(n0 + row0) * K + k0 + cs0 * 8], bb + dst0);
        gld16(&BT[(size_t)(n0 + row1) * K + k0 + cs1 * 8], bb + dst1);
    };

    f32x4 acc[8][4] = {};
    STAGE(0, kbase);
    STAGE(1, kbase + 32);
    asm volatile("s_waitcnt vmcnt(4)" ::: "memory");
    __builtin_amdgcn_s_barrier();
    __builtin_amdgcn_sched_barrier(0);

    int rchk = (lr >> 1) & 3;
    int fcol = ((lh ^ rchk) * 8);
    for (int kt = 0; kt < nk; ++kt) {
        int b0 = kt % 3;
        const bf16* ab = a_lds + b0 * 8192;
        const bf16* bb = b_lds + b0 * 8192;
        bf16x8 af[8], bf[4];
        #pragma unroll
        for (int m = 0; m < 8; m++)
            af[m] = *(const bf16x8*)&ab[(wr * 128 + m * 16 + lr) * 32 + fcol];
        #pragma unroll
        for (int n = 0; n < 4; n++)
            bf[n] = *(const bf16x8*)&bb[(wc * 64 + n * 16 + lr) * 32 + fcol];
        if (kt + 2 < nk) {
            STAGE((kt + 2) % 3, kbase + (kt + 2) * 32);
            asm volatile("s_waitcnt vmcnt(4)" ::: "memory");
        } else {
            asm volatile("s_waitcnt vmcnt(0)" ::: "memory");
        }
        __builtin_amdgcn_s_setprio(1);
        #pragma unroll
        for (int m = 0; m < 8; m++)
            #pragma unroll
            for (int n = 0; n < 4; n++)
                acc[m][n] = MFMA16(af[m], bf[n], acc[m][n]);
        __builtin_amdgcn_s_setprio(0);
        __builtin_amdgcn_s_barrier();
        __builtin_amdgcn_sched_barrier(0);
    }

    #pragma unroll
    for (int m = 0; m < 8; m++) {
        #pragma unroll
        for (int n = 0; n < 4; n++) {
            int col = n0 + wc * 64 + n * 16 + lr;
            float bv = (MODE == 3) ? 0.f : bias[col];
            #pragma unroll
            for (int r = 0; r < 4; r++) {
                int row = m0 + wr * 128 + m * 16 + lh * 4 + r;
                float vv = acc[m][n][r] + bv;
                if (MODE == 2) vv = 0.5f * vv * (1.f + erff(vv * 0.70710678118654752f));
                if (MODE == 3) ((float*)outp)[((size_t)z * M + row) * N + col] = vv;
                else           ((bf16*)outp)[(size_t)row * N + col] = (bf16)vv;
            }
        }
    }
}

// ---------------- split-K reduce: out = sum_z part[z] + bias + res (f32, N=1024) ----------------
__global__ __launch_bounds__(256) void reduce4(const float* __restrict__ part,
                                               const float* __restrict__ bias,
                                               const float* __restrict__ res,
                                               float* __restrict__ out) {
    int i = blockIdx.x * 256 + threadIdx.x;
    const float4* p = (const float4*)part;
    const size_t s4 = (size_t)M_ * 1024 / 4;
    float4 a = p[i], b = p[i + s4], c = p[i + 2 * s4], d = p[i + 3 * s4];
    float4 bv = ((const float4*)bias)[i & 255];
    float4 rv = ((const float4*)res)[i];
    float4 o;
    o.x = a.x + b.x + c.x + d.x + bv.x + rv.x;
    o.y = a.y + b.y + c.y + d.y + bv.y + rv.y;
    o.z = a.z + b.z + c.z + d.z + bv.z + rv.z;
    o.w = a.w + b.w + c.w + d.w + bv.w + rv.w;
    ((float4*)out)[i] = o;
}

// ------- fused split-K reduce + LayerNorm: x2 = sum_z part + bias + res; h2 = LN(x2) -------
__global__ __launch_bounds__(256) void reduce_ln(const float* __restrict__ part,
                                                 const float* __restrict__ bias,
                                                 const float* __restrict__ res,
                                                 const float* __restrict__ g,
                                                 const float* __restrict__ sh,
                                                 float* __restrict__ x2,
                                                 bf16* __restrict__ h2) {
    __shared__ float s_sum[4], s_ss[4];
    int row = blockIdx.x, t = threadIdx.x;
    int wv = t >> 6, lane = t & 63;
    size_t i = (size_t)row * 256 + t;
    const float4* p = (const float4*)part;
    const size_t s4 = (size_t)M_ * 1024 / 4;
    float4 a = p[i], b = p[i + s4], c = p[i + 2 * s4], d = p[i + 3 * s4];
    float4 bv = ((const float4*)bias)[t];
    float4 rv = ((const float4*)res)[i];
    float4 v;
    v.x = a.x + b.x + c.x + d.x + bv.x + rv.x;
    v.y = a.y + b.y + c.y + d.y + bv.y + rv.y;
    v.z = a.z + b.z + c.z + d.z + bv.z + rv.z;
    v.w = a.w + b.w + c.w + d.w + bv.w + rv.w;
    ((float4*)x2)[i] = v;
    float sum = v.x + v.y + v.z + v.w;
    float ss  = v.x * v.x + v.y * v.y + v.z * v.z + v.w * v.w;
    #pragma unroll
    for (int o = 32; o; o >>= 1) { sum += __shfl_xor(sum, o); ss += __shfl_xor(ss, o); }
    if (lane == 0) { s_sum[wv] = sum; s_ss[wv] = ss; }
    __syncthreads();
    sum = s_sum[0] + s_sum[1] + s_sum[2] + s_sum[3];
    ss  = s_ss[0] + s_ss[1] + s_ss[2] + s_ss[3];
    float mean = sum * (1.f / 1024.f);
    float var  = (ss - 1024.f * mean * mean) * (1.f / 1023.f);
    float inv  = 1.f / (sqrtf(var) + 1e-5f);
    float4 gv = ((const float4*)g)[t], sv = ((const float4*)sh)[t];
    bf16x4 o4;
    o4[0] = (bf16)((v.x - mean) * inv * gv.x + sv.x);
    o4[1] = (bf16)((v.y - mean) * inv * gv.y + sv.y);
    o4[2] = (bf16)((v.z - mean) * inv * gv.z + sv.z);
    o4[3] = (bf16)((v.w - mean) * inv * gv.w + sv.w);
    *(bf16x4*)&h2[(size_t)row * D_ + t * 4] = o4;
}

// ---------------- causal flash attention v4: QBLK=64 (4 waves x 16 q), KVBLK=64 ----------------
// Round-4 structure (grid 1024 blocks) + kept wins: diagonal-only mask, Q pre-scale (1/8 exact),
// T14 reg prefetch of next K/V tile, T13 defer-max (skip rescale when pmax <= mrow+8).
__global__ __launch_bounds__(256) void attn_kernel(const bf16* __restrict__ qkv,
                                                   const bf16* __restrict__ VT,
                                                   bf16* __restrict__ ctx) {
    __shared__ __align__(16) bf16 k_lds[64 * 72];
    __shared__ __align__(16) bf16 vt_lds[64 * 72];
    __shared__ __align__(16) bf16 p_lds[4 * 16 * 72];
    int bh = blockIdx.x; int b = bh >> 4, h = bh & 15;
    int qt = gridDim.y - 1 - blockIdx.y;   // heavy-first
    int q0 = qt * 64;
    int tid = threadIdx.x, w = tid >> 6, lane = tid & 63;
    int lr = lane & 15, lh = lane >> 4;
    const size_t RS = QKVN;
    const bf16* qbase = qkv + (size_t)b * S_ * RS + h * 64;
    const bf16* kbase = qbase + 1024;
    const bf16* vtb = VT + (size_t)bh * 64 * S_;

    // Q fragments pre-scaled by 1/8 (power of 2 -> exact in bf16)
    int qrow = q0 + w * 16 + lr;
    bf16x8 aq[2];
    #pragma unroll
    for (int dc = 0; dc < 2; dc++) {
        bf16x8 t8 = *(const bf16x8*)&qbase[(size_t)qrow * RS + dc * 32 + lh * 8];
        #pragma unroll
        for (int j = 0; j < 8; j++) t8[j] = (bf16)((float)t8[j] * 0.125f);
        aq[dc] = t8;
    }

    f32x4 o_acc[4] = {};
    float mrow[4], lrow[4];
    #pragma unroll
    for (int r = 0; r < 4; r++) { mrow[r] = -1e30f; lrow[r] = 0.f; }

    int er = tid >> 3, ecg = tid & 7;   // 32 rows x 8 col-granules per pass, 2 passes
    int ntile = qt + 1;
    // prologue: tile 0 loads into regs (T14)
    bf16x8 kreg0 = *(const bf16x8*)&kbase[(size_t)er * RS + ecg * 8];
    bf16x8 kreg1 = *(const bf16x8*)&kbase[(size_t)(er + 32) * RS + ecg * 8];
    bf16x8 vreg0 = *(const bf16x8*)&vtb[(size_t)er * S_ + ecg * 8];
    bf16x8 vreg1 = *(const bf16x8*)&vtb[(size_t)(er + 32) * S_ + ecg * 8];

    for (int t = 0; t < ntile; t++) {
        int kv0 = t * 64;
        *(bf16x8*)&k_lds [er * 72 + ecg * 8]        = kreg0;
        *(bf16x8*)&k_lds [(er + 32) * 72 + ecg * 8] = kreg1;
        *(bf16x8*)&vt_lds[er * 72 + ecg * 8]        = vreg0;
        *(bf16x8*)&vt_lds[(er + 32) * 72 + ecg * 8] = vreg1;
        __syncthreads();
        if (t + 1 < ntile) {    // T14: issue next tile's loads; consumed next iteration
            int kn = kv0 + 64;
            kreg0 = *(const bf16x8*)&kbase[(size_t)(kn + er) * RS + ecg * 8];
            kreg1 = *(const bf16x8*)&kbase[(size_t)(kn + er + 32) * RS + ecg * 8];
            vreg0 = *(const bf16x8*)&vtb[(size_t)er * S_ + kn + ecg * 8];
            vreg1 = *(const bf16x8*)&vtb[(size_t)(er + 32) * S_ + kn + ecg * 8];
        }

        // QK^T: 16 q x 64 kv (4 C-frags), K over d=64 (2 chunks)
        f32x4 sc[4] = {};
        #pragma unroll
        for (int kf = 0; kf < 4; kf++)
            #pragma unroll
            for (int dc = 0; dc < 2; dc++) {
                bf16x8 bk = *(const bf16x8*)&k_lds[(kf * 16 + lr) * 72 + dc * 32 + lh * 8];
                sc[kf] = MFMA16(aq[dc], bk, sc[kf]);
            }

        // causal mask: only the diagonal tile needs it (kv0 == q0)
        if (t == ntile - 1) {
            #pragma unroll
            for (int kf = 0; kf < 4; kf++) {
                int kvg = kv0 + kf * 16 + lr;
                #pragma unroll
                for (int r = 0; r < 4; r++) {
                    int qg = q0 + w * 16 + lh * 4 + r;
                    if (kvg > qg) sc[kf][r] = -100000.0f;
                }
            }
        }

        // row max: in-thread across kf, then 16-lane butterfly
        float pmax[4];
        #pragma unroll
        for (int r = 0; r < 4; r++)
            pmax[r] = fmaxf(fmaxf(sc[0][r], sc[1][r]), fmaxf(sc[2][r], sc[3][r]));
        #pragma unroll
        for (int o = 1; o < 16; o <<= 1)
            #pragma unroll
            for (int r = 0; r < 4; r++)
                pmax[r] = fmaxf(pmax[r], __shfl_xor(pmax[r], o));

        // T13 defer-max: skip rescale unless some row's max grew past mrow+8
        bool ok = true;
        #pragma unroll
        for (int r = 0; r < 4; r++) ok = ok && (pmax[r] <= mrow[r] + 8.f);
        if (!__all(ok)) {
            #pragma unroll
            for (int r = 0; r < 4; r++) {
                float mn = fmaxf(mrow[r], pmax[r]);
                float s = __expf(mrow[r] - mn);
                mrow[r] = mn;
                lrow[r] *= s;
                #pragma unroll
                for (int df = 0; df < 4; df++) o_acc[df][r] *= s;
            }
        }

        float psum[4] = {0.f, 0.f, 0.f, 0.f};
        #pragma unroll
        for (int kf = 0; kf < 4; kf++)
            #pragma unroll
            for (int r = 0; r < 4; r++) {
                float p = __expf(sc[kf][r] - mrow[r]);
                sc[kf][r] = p;
                psum[r] += p;
            }
        #pragma unroll
        for (int o = 1; o < 16; o <<= 1)
            #pragma unroll
            for (int r = 0; r < 4; r++) psum[r] += __shfl_xor(psum[r], o);
        #pragma unroll
        for (int r = 0; r < 4; r++) lrow[r] += psum[r];

        // P (C-layout) -> per-wave LDS -> A-layout fragments
        bf16* pw = &p_lds[w * 16 * 72];
        #pragma unroll
        for (int kf = 0; kf < 4; kf++)
            #pragma unroll
            for (int r = 0; r < 4; r++)
                pw[(lh * 4 + r) * 72 + kf * 16 + lr] = (bf16)sc[kf][r];
        asm volatile("s_waitcnt lgkmcnt(0)" ::: "memory");
        __builtin_amdgcn_sched_barrier(0);
        bf16x8 ap[2];
        ap[0] = *(const bf16x8*)&pw[lr * 72 + lh * 8];
        ap[1] = *(const bf16x8*)&pw[lr * 72 + 32 + lh * 8];
        #pragma unroll
        for (int df = 0; df < 4; df++) {
            #pragma unroll
            for (int kc = 0; kc < 2; kc++) {
                bf16x8 bv = *(const bf16x8*)&vt_lds[(df * 16 + lr) * 72 + kc * 32 + lh * 8];
                o_acc[df] = MFMA16(ap[kc], bv, o_acc[df]);
            }
        }
        __syncthreads();
    }

    #pragma unroll
    for (int df = 0; df < 4; df++)
        #pragma unroll
        for (int r = 0; r < 4; r++) {
            int row = q0 + w * 16 + lh * 4 + r;
            int col = h * 64 + df * 16 + lr;
            ctx[((size_t)b * S_ + row) * D_ + col] = (bf16)(o_acc[df][r] / lrow[r]);
        }
}

extern "C" void kernel_launch(void* const* d_in, const int* in_sizes, int n_in,
                              void* d_out, int out_size, void* d_ws, size_t ws_size,
                              hipStream_t stream) {
    const float* x  = (const float*)d_in[0];
    const float* Wq = (const float*)d_in[1];
    const float* bq = (const float*)d_in[2];
    const float* Wk = (const float*)d_in[3];
    const float* bk = (const float*)d_in[4];
    const float* Wv = (const float*)d_in[5];
    const float* bv = (const float*)d_in[6];
    const float* Wo = (const float*)d_in[7];
    const float* bo = (const float*)d_in[8];
    const float* W1 = (const float*)d_in[9];
    const float* b1 = (const float*)d_in[10];
    const float* W2 = (const float*)d_in[11];
    const float* b2 = (const float*)d_in[12];
    const float* g1 = (const float*)d_in[13];
    const float* s1 = (const float*)d_in[14];
    const float* g2 = (const float*)d_in[15];
    const float* s2 = (const float*)d_in[16];
    float* out = (float*)d_out;

    char* ws = (char*)d_ws;
    size_t off = 0;
    auto alloc = [&](size_t bytes) -> char* {
        char* p = ws + off; off += (bytes + 255) & ~(size_t)255; return p;
    };
    bf16*  wt_qkv = (bf16*)alloc((size_t)QKVN * D_ * 2);
    bf16*  wt_o   = (bf16*)alloc((size_t)D_ * D_ * 2);
    bf16*  wt_1   = (bf16*)alloc((size_t)FF_ * D_ * 2);
    bf16*  wt_2   = (bf16*)alloc((size_t)D_ * FF_ * 2);
    float* qkvb   = (float*)alloc((size_t)QKVN * 4);
    bf16*  h1     = (bf16*)alloc((size_t)M_ * D_ * 2);
    bf16*  qkv    = (bf16*)alloc((size_t)M_ * QKVN * 2);
    bf16*  vtbuf  = (bf16*)alloc((size_t)M_ * D_ * 2);
    bf16*  ctx    = (bf16*)alloc((size_t)M_ * D_ * 2);
    float* x2     = (float*)alloc((size_t)M_ * D_ * 4);
    bf16*  h2     = (bf16*)alloc((size_t)M_ * D_ * 2);
    bf16*  gbuf   = (bf16*)alloc((size_t)M_ * FF_ * 2);
    float* part   = (float*)alloc((size_t)4 * M_ * D_ * 4);   // split-K partials (shared)

    // weight prep
    transpose_cast<<<dim3(16, 16), 256, 0, stream>>>(Wq, wt_qkv, D_, D_);
    transpose_cast<<<dim3(16, 16), 256, 0, stream>>>(Wk, wt_qkv + (size_t)D_ * D_, D_, D_);
    transpose_cast<<<dim3(16, 16), 256, 0, stream>>>(Wv, wt_qkv + (size_t)2 * D_ * D_, D_, D_);
    transpose_cast<<<dim3(16, 16), 256, 0, stream>>>(Wo, wt_o, D_, D_);
    transpose_cast<<<dim3(16, 64), 256, 0, stream>>>(W1, wt_1, D_, FF_);
    transpose_cast<<<dim3(64, 16), 256, 0, stream>>>(W2, wt_2, FF_, D_);
    concat3<<<12, 256, 0, stream>>>(bq, bk, bv, qkvb);

    // block
    ln_kernel<<<M_ / 4, 256, 0, stream>>>(x, g1, s1, h1);
    gemm256<0><<<dim3(QKVN / 256, M_ / 256, 1), 512, 0, stream>>>(h1, wt_qkv, qkvb, qkv, M_, QKVN, D_, D_);
    transpose_v<<<dim3(S_ / 64, B_ * H_), 256, 0, stream>>>(qkv, vtbuf);
    attn_kernel<<<dim3(B_ * H_, S_ / 64), 256, 0, stream>>>(qkv, vtbuf, ctx);
    gemm256<3><<<dim3(D_ / 256, M_ / 256, 4), 512, 0, stream>>>(ctx, wt_o, nullptr, part, M_, D_, D_, D_ / 4);
    reduce_ln<<<M_, 256, 0, stream>>>(part, bo, x, g2, s2, x2, h2);
    gemm256<2><<<dim3(FF_ / 256, M_ / 256, 1), 512, 0, stream>>>(h2, wt_1, b1, gbuf, M_, FF_, D_, D_);
    gemm256<3><<<dim3(D_ / 256, M_ / 256, 4), 512, 0, stream>>>(gbuf, wt_2, nullptr, part, M_, D_, FF_, FF_ / 4);
    reduce4<<<(M_ * D_) / 1024, 256, 0, stream>>>(part, b2, x2, out);
}

// Round 7
// 373.393 us; speedup vs baseline: 1.1356x; 1.0371x over previous
//
#include <hip/hip_runtime.h>
#include <hip/hip_bf16.h>
#include <math.h>

#define D_   1024
#define H_   16
#define HD_  64
#define S_   2048
#define B_   2
#define FF_  4096
#define M_   (B_*S_)      // 4096 rows
#define QKVN (3*D_)       // 3072

typedef __bf16 bf16;
typedef bf16 bf16x8 __attribute__((ext_vector_type(8)));
typedef bf16 bf16x4 __attribute__((ext_vector_type(4)));
typedef float f32x4 __attribute__((ext_vector_type(4)));

#define MFMA16(a,b,c) __builtin_amdgcn_mfma_f32_16x16x32_bf16(a,b,c,0,0,0)

// async global->LDS 16B per lane (wave-uniform LDS base + lane*16)
__device__ __forceinline__ void gld16(const void* g, void* l) {
    __builtin_amdgcn_global_load_lds(
        (const __attribute__((address_space(1))) void*)g,
        (__attribute__((address_space(3))) void*)l, 16, 0, 0);
}

// ---------------- weight transpose + cast: W[K][N] f32 -> WT[N][K] bf16 (float4 loads) ----------------
__global__ __launch_bounds__(256) void transpose_cast(const float* __restrict__ W,
                                                      bf16* __restrict__ WT,
                                                      int K, int N) {
    __shared__ float t[64][65];
    int k0 = blockIdx.x * 64, n0 = blockIdx.y * 64;
    int tid = threadIdx.x;
    int tr = tid >> 4, tc = tid & 15;
    #pragma unroll
    for (int i = 0; i < 4; i++) {
        int r = tr + i * 16;
        float4 v = *(const float4*)&W[(size_t)(k0 + r) * N + n0 + tc * 4];
        t[r][tc * 4 + 0] = v.x; t[r][tc * 4 + 1] = v.y;
        t[r][tc * 4 + 2] = v.z; t[r][tc * 4 + 3] = v.w;
    }
    __syncthreads();
    #pragma unroll
    for (int i = 0; i < 4; i++) {
        int r = tr + i * 16;
        bf16x4 o;
        #pragma unroll
        for (int j = 0; j < 4; j++) o[j] = (bf16)t[tc * 4 + j][r];
        *(bf16x4*)&WT[(size_t)(n0 + r) * K + k0 + tc * 4] = o;
    }
}

// ---------------- transpose V section of qkv into VT[bh][d][s] ----------------
__global__ __launch_bounds__(256) void transpose_v(const bf16* __restrict__ qkv,
                                                   bf16* __restrict__ VT) {
    __shared__ __align__(16) bf16 t[64][72];
    int bh = blockIdx.y; int b = bh >> 4, h = bh & 15;
    int s0 = blockIdx.x * 64;
    const bf16* vbase = qkv + (size_t)b * S_ * QKVN + 2048 + h * 64;
    int tid = threadIdx.x;
    #pragma unroll
    for (int i = 0; i < 2; i++) {
        int e = tid + i * 256; int r = e >> 3, cg = e & 7;
        *(bf16x8*)&t[r][cg * 8] = *(const bf16x8*)&vbase[(size_t)(s0 + r) * QKVN + cg * 8];
    }
    __syncthreads();
    #pragma unroll
    for (int i = 0; i < 2; i++) {
        int e = tid + i * 256; int d = e >> 3, cg = e & 7;
        bf16x8 v;
        #pragma unroll
        for (int j = 0; j < 8; j++) v[j] = t[cg * 8 + j][d];
        *(bf16x8*)&VT[((size_t)bh * 64 + d) * S_ + s0 + cg * 8] = v;
    }
}

// ---------------- concat q,k,v biases into one [3072] buffer ----------------
__global__ void concat3(const float* __restrict__ a, const float* __restrict__ b,
                        const float* __restrict__ c, float* __restrict__ o) {
    int i = blockIdx.x * 256 + threadIdx.x;
    o[i] = (i < 1024) ? a[i] : (i < 2048 ? b[i - 1024] : c[i - 2048]);
}

// ---------------- layernorm (ddof=1, eps on std) f32 in -> bf16 out ----------------
__global__ __launch_bounds__(256) void ln_kernel(const float* __restrict__ x,
                                                 const float* __restrict__ g,
                                                 const float* __restrict__ sh,
                                                 bf16* __restrict__ out) {
    int row = blockIdx.x * 4 + (threadIdx.x >> 6);
    int lane = threadIdx.x & 63;
    const float4* xr = (const float4*)(x + (size_t)row * D_);
    float4 v[4]; float sum = 0.f, ss = 0.f;
    #pragma unroll
    for (int c = 0; c < 4; c++) {
        v[c] = xr[lane + 64 * c];
        sum += v[c].x + v[c].y + v[c].z + v[c].w;
        ss  += v[c].x * v[c].x + v[c].y * v[c].y + v[c].z * v[c].z + v[c].w * v[c].w;
    }
    #pragma unroll
    for (int o = 32; o; o >>= 1) { sum += __shfl_xor(sum, o); ss += __shfl_xor(ss, o); }
    float mean = sum * (1.f / 1024.f);
    float var  = (ss - 1024.f * mean * mean) * (1.f / 1023.f);
    float inv  = 1.f / (sqrtf(var) + 1e-5f);
    const float4* gp = (const float4*)g;
    const float4* sp = (const float4*)sh;
    bf16x4* op = (bf16x4*)(out + (size_t)row * D_);
    #pragma unroll
    for (int c = 0; c < 4; c++) {
        int idx = lane + 64 * c;
        float4 gv = gp[idx], sv = sp[idx];
        float y0 = (v[c].x - mean) * inv * gv.x + sv.x;
        float y1 = (v[c].y - mean) * inv * gv.y + sv.y;
        float y2 = (v[c].z - mean) * inv * gv.z + sv.z;
        float y3 = (v[c].w - mean) * inv * gv.w + sv.w;
        op[idx] = (bf16x4){(bf16)y0, (bf16)y1, (bf16)y2, (bf16)y3};
    }
}

// ================= 256x256 BK=32 8-wave triple-buffered counted-vmcnt GEMM =================
// (unchanged from round 4 — see comments there)
template<int MODE>
__global__ __launch_bounds__(512, 2) void gemm256(const bf16* __restrict__ A,
                                                  const bf16* __restrict__ BT,
                                                  const float* __restrict__ bias,
                                                  void* __restrict__ outp,
                                                  int M, int N, int K, int KSLICE) {
    __shared__ __align__(16) bf16 a_lds[3 * 256 * 32];
    __shared__ __align__(16) bf16 b_lds[3 * 256 * 32];
    int tid = threadIdx.x, w = tid >> 6, lane = tid & 63;
    int gx = gridDim.x, gxy = gx * gridDim.y;
    int nwg = gxy * gridDim.z;
    int flat = blockIdx.z * gxy + blockIdx.y * gx + blockIdx.x;
    int chunk = nwg >> 3;
    int swz = (flat & 7) * chunk + (flat >> 3);
    int z = swz / gxy, rem = swz - z * gxy;
    int m0 = (rem / gx) * 256, n0 = (rem % gx) * 256;
    int kbase = z * KSLICE;
    int nk = KSLICE >> 5;
    int lr = lane & 15, lh = lane >> 4;
    int wr = w >> 2, wc = w & 3;

    int g0 = w * 64 + lane;
    int row0 = g0 >> 2, cs0 = (g0 & 3) ^ ((row0 >> 1) & 3);
    int g1 = g0 + 512;
    int row1 = g1 >> 2, cs1 = (g1 & 3) ^ ((row1 >> 1) & 3);
    int dst0 = w * 512;
    int dst1 = w * 512 + 4096;

    auto STAGE = [&](int buf, int k0) {
        bf16* ab = a_lds + buf * 8192;
        bf16* bb = b_lds + buf * 8192;
        gld16(&A [(size_t)(m0 + row0) * K + k0 + cs0 * 8], ab + dst0);
        gld16(&A [(size_t)(m0 + row1) * K + k0 + cs1 * 8], ab + dst1);
        gld16(&BT[(size_t)(n0 + row0) * K + k0 + cs0 * 8], bb + dst0);
        gld16(&BT[(size_t)(n0 + row1) * K + k0 + cs1 * 8], bb + dst1);
    };

    f32x4 acc[8][4] = {};
    STAGE(0, kbase);
    STAGE(1, kbase + 32);
    asm volatile("s_waitcnt vmcnt(4)" ::: "memory");
    __builtin_amdgcn_s_barrier();
    __builtin_amdgcn_sched_barrier(0);

    int rchk = (lr >> 1) & 3;
    int fcol = ((lh ^ rchk) * 8);
    for (int kt = 0; kt < nk; ++kt) {
        int b0 = kt % 3;
        const bf16* ab = a_lds + b0 * 8192;
        const bf16* bb = b_lds + b0 * 8192;
        bf16x8 af[8], bf[4];
        #pragma unroll
        for (int m = 0; m < 8; m++)
            af[m] = *(const bf16x8*)&ab[(wr * 128 + m * 16 + lr) * 32 + fcol];
        #pragma unroll
        for (int n = 0; n < 4; n++)
            bf[n] = *(const bf16x8*)&bb[(wc * 64 + n * 16 + lr) * 32 + fcol];
        if (kt + 2 < nk) {
            STAGE((kt + 2) % 3, kbase + (kt + 2) * 32);
            asm volatile("s_waitcnt vmcnt(4)" ::: "memory");
        } else {
            asm volatile("s_waitcnt vmcnt(0)" ::: "memory");
        }
        __builtin_amdgcn_s_setprio(1);
        #pragma unroll
        for (int m = 0; m < 8; m++)
            #pragma unroll
            for (int n = 0; n < 4; n++)
                acc[m][n] = MFMA16(af[m], bf[n], acc[m][n]);
        __builtin_amdgcn_s_setprio(0);
        __builtin_amdgcn_s_barrier();
        __builtin_amdgcn_sched_barrier(0);
    }

    #pragma unroll
    for (int m = 0; m < 8; m++) {
        #pragma unroll
        for (int n = 0; n < 4; n++) {
            int col = n0 + wc * 64 + n * 16 + lr;
            float bv = (MODE == 3) ? 0.f : bias[col];
            #pragma unroll
            for (int r = 0; r < 4; r++) {
                int row = m0 + wr * 128 + m * 16 + lh * 4 + r;
                float vv = acc[m][n][r] + bv;
                if (MODE == 2) vv = 0.5f * vv * (1.f + erff(vv * 0.70710678118654752f));
                if (MODE == 3) ((float*)outp)[((size_t)z * M + row) * N + col] = vv;
                else           ((bf16*)outp)[(size_t)row * N + col] = (bf16)vv;
            }
        }
    }
}

// ---------------- split-K reduce: out = sum_z part[z] + bias + res (f32, N=1024) ----------------
__global__ __launch_bounds__(256) void reduce4(const float* __restrict__ part,
                                               const float* __restrict__ bias,
                                               const float* __restrict__ res,
                                               float* __restrict__ out) {
    int i = blockIdx.x * 256 + threadIdx.x;
    const float4* p = (const float4*)part;
    const size_t s4 = (size_t)M_ * 1024 / 4;
    float4 a = p[i], b = p[i + s4], c = p[i + 2 * s4], d = p[i + 3 * s4];
    float4 bv = ((const float4*)bias)[i & 255];
    float4 rv = ((const float4*)res)[i];
    float4 o;
    o.x = a.x + b.x + c.x + d.x + bv.x + rv.x;
    o.y = a.y + b.y + c.y + d.y + bv.y + rv.y;
    o.z = a.z + b.z + c.z + d.z + bv.z + rv.z;
    o.w = a.w + b.w + c.w + d.w + bv.w + rv.w;
    ((float4*)out)[i] = o;
}

// ------- fused split-K reduce + LayerNorm: x2 = sum_z part + bias + res; h2 = LN(x2) -------
__global__ __launch_bounds__(256) void reduce_ln(const float* __restrict__ part,
                                                 const float* __restrict__ bias,
                                                 const float* __restrict__ res,
                                                 const float* __restrict__ g,
                                                 const float* __restrict__ sh,
                                                 float* __restrict__ x2,
                                                 bf16* __restrict__ h2) {
    __shared__ float s_sum[4], s_ss[4];
    int row = blockIdx.x, t = threadIdx.x;
    int wv = t >> 6, lane = t & 63;
    size_t i = (size_t)row * 256 + t;
    const float4* p = (const float4*)part;
    const size_t s4 = (size_t)M_ * 1024 / 4;
    float4 a = p[i], b = p[i + s4], c = p[i + 2 * s4], d = p[i + 3 * s4];
    float4 bv = ((const float4*)bias)[t];
    float4 rv = ((const float4*)res)[i];
    float4 v;
    v.x = a.x + b.x + c.x + d.x + bv.x + rv.x;
    v.y = a.y + b.y + c.y + d.y + bv.y + rv.y;
    v.z = a.z + b.z + c.z + d.z + bv.z + rv.z;
    v.w = a.w + b.w + c.w + d.w + bv.w + rv.w;
    ((float4*)x2)[i] = v;
    float sum = v.x + v.y + v.z + v.w;
    float ss  = v.x * v.x + v.y * v.y + v.z * v.z + v.w * v.w;
    #pragma unroll
    for (int o = 32; o; o >>= 1) { sum += __shfl_xor(sum, o); ss += __shfl_xor(ss, o); }
    if (lane == 0) { s_sum[wv] = sum; s_ss[wv] = ss; }
    __syncthreads();
    sum = s_sum[0] + s_sum[1] + s_sum[2] + s_sum[3];
    ss  = s_ss[0] + s_ss[1] + s_ss[2] + s_ss[3];
    float mean = sum * (1.f / 1024.f);
    float var  = (ss - 1024.f * mean * mean) * (1.f / 1023.f);
    float inv  = 1.f / (sqrtf(var) + 1e-5f);
    float4 gv = ((const float4*)g)[t], sv = ((const float4*)sh)[t];
    bf16x4 o4;
    o4[0] = (bf16)((v.x - mean) * inv * gv.x + sv.x);
    o4[1] = (bf16)((v.y - mean) * inv * gv.y + sv.y);
    o4[2] = (bf16)((v.z - mean) * inv * gv.z + sv.z);
    o4[3] = (bf16)((v.w - mean) * inv * gv.w + sv.w);
    *(bf16x4*)&h2[(size_t)row * D_ + t * 4] = o4;
}

// ---------------- causal flash attention v5: swapped-operand QK^T, lane-local softmax ----------------
// QBLK=64 (4 waves x 16 q), KVBLK=64.  S^T = MFMA(K_as_A, Q_as_B): lane (q=lane&15) holds
// P[q][kv], kv = kf*16 + lh*4 + r.  Row stats are per-lane scalars (2 shfl_xor to merge lh groups).
// V^T LDS kv-columns are stored under quad-permutation p(o) = (o&8) + 2*(o&3) + ((o>>2)&1)
// (applied to BOTH PV operands' contraction index -> sum unchanged) so the PV B-fragment is
// exactly the lane's own packed p values: ZERO cross-lane movement, no P-LDS roundtrip.
__global__ __launch_bounds__(256) void attn_kernel(const bf16* __restrict__ qkv,
                                                   const bf16* __restrict__ VT,
                                                   bf16* __restrict__ ctx) {
    __shared__ __align__(16) bf16 k_lds[64 * 72];
    __shared__ __align__(16) bf16 vt_lds[64 * 72];
    int bh = blockIdx.x; int b = bh >> 4, h = bh & 15;
    int qt = gridDim.y - 1 - blockIdx.y;   // heavy-first
    int q0 = qt * 64;
    int tid = threadIdx.x, w = tid >> 6, lane = tid & 63;
    int lr = lane & 15, lh = lane >> 4;
    const size_t RS = QKVN;
    const bf16* qbase = qkv + (size_t)b * S_ * RS + h * 64;
    const bf16* kbase = qbase + 1024;
    const bf16* vtb = VT + (size_t)bh * 64 * S_;

    // Q fragments (B-operand), pre-scaled by 1/8 (power of 2 -> exact in bf16)
    int qrow = q0 + w * 16 + lr;
    bf16x8 aq[2];
    #pragma unroll
    for (int dc = 0; dc < 2; dc++) {
        bf16x8 t8 = *(const bf16x8*)&qbase[(size_t)qrow * RS + dc * 32 + lh * 8];
        #pragma unroll
        for (int j = 0; j < 8; j++) t8[j] = (bf16)((float)t8[j] * 0.125f);
        aq[dc] = t8;
    }

    f32x4 oT[4] = {};            // O^T frags [df]: row=d_local=lh*4+r, col=q=lr
    float mrow = -1e30f, lrow = 0.f;

    int er = tid >> 3, ecg = tid & 7;   // 32 rows x 8 col-granules per pass, 2 passes
    // V column quad-permutation for this thread's staged granule (quads 2*ecg, 2*ecg+1)
    int o0 = ecg * 2, o1 = o0 + 1;
    int p0 = (o0 & 8) + 2 * (o0 & 3) + ((o0 >> 2) & 1);
    int p1 = (o1 & 8) + 2 * (o1 & 3) + ((o1 >> 2) & 1);

    int ntile = qt + 1;
    // prologue: tile 0 loads into regs (T14)
    bf16x8 kreg0 = *(const bf16x8*)&kbase[(size_t)er * RS + ecg * 8];
    bf16x8 kreg1 = *(const bf16x8*)&kbase[(size_t)(er + 32) * RS + ecg * 8];
    bf16x8 vreg0 = *(const bf16x8*)&vtb[(size_t)er * S_ + ecg * 8];
    bf16x8 vreg1 = *(const bf16x8*)&vtb[(size_t)(er + 32) * S_ + ecg * 8];

    for (int t = 0; t < ntile; t++) {
        int kv0 = t * 64;
        *(bf16x8*)&k_lds[er * 72 + ecg * 8]        = kreg0;
        *(bf16x8*)&k_lds[(er + 32) * 72 + ecg * 8] = kreg1;
        // permuted V store: two b64 halves per staged granule
        {
            bf16x4 lo0 = {vreg0[0], vreg0[1], vreg0[2], vreg0[3]};
            bf16x4 hi0 = {vreg0[4], vreg0[5], vreg0[6], vreg0[7]};
            bf16x4 lo1 = {vreg1[0], vreg1[1], vreg1[2], vreg1[3]};
            bf16x4 hi1 = {vreg1[4], vreg1[5], vreg1[6], vreg1[7]};
            *(bf16x4*)&vt_lds[er * 72 + p0 * 4]        = lo0;
            *(bf16x4*)&vt_lds[er * 72 + p1 * 4]        = hi0;
            *(bf16x4*)&vt_lds[(er + 32) * 72 + p0 * 4] = lo1;
            *(bf16x4*)&vt_lds[(er + 32) * 72 + p1 * 4] = hi1;
        }
        __syncthreads();
        if (t + 1 < ntile) {    // T14: issue next tile's loads; consumed next iteration
            int kn = kv0 + 64;
            kreg0 = *(const bf16x8*)&kbase[(size_t)(kn + er) * RS + ecg * 8];
            kreg1 = *(const bf16x8*)&kbase[(size_t)(kn + er + 32) * RS + ecg * 8];
            vreg0 = *(const bf16x8*)&vtb[(size_t)er * S_ + kn + ecg * 8];
            vreg1 = *(const bf16x8*)&vtb[(size_t)(er + 32) * S_ + kn + ecg * 8];
        }

        // S^T = K · Q^T: A = K frag (same LDS read as before), B = Q regs
        f32x4 sc[4] = {};
        #pragma unroll
        for (int kf = 0; kf < 4; kf++)
            #pragma unroll
            for (int dc = 0; dc < 2; dc++) {
                bf16x8 ak = *(const bf16x8*)&k_lds[(kf * 16 + lr) * 72 + dc * 32 + lh * 8];
                sc[kf] = MFMA16(ak, aq[dc], sc[kf]);
            }

        // causal mask: only the diagonal tile (kv0 == q0); qg per-lane constant
        if (t == ntile - 1) {
            int qg = q0 + w * 16 + lr;
            #pragma unroll
            for (int kf = 0; kf < 4; kf++)
                #pragma unroll
                for (int r = 0; r < 4; r++) {
                    int kvg = kv0 + kf * 16 + lh * 4 + r;
                    if (kvg > qg) sc[kf][r] = -100000.0f;
                }
        }

        // row max: 15 in-lane fmax + 2 shfl (merge the 4 lh slices of this q-row)
        float pmax = sc[0][0];
        #pragma unroll
        for (int kf = 0; kf < 4; kf++)
            #pragma unroll
            for (int r = 0; r < 4; r++) pmax = fmaxf(pmax, sc[kf][r]);
        pmax = fmaxf(pmax, __shfl_xor(pmax, 16));
        pmax = fmaxf(pmax, __shfl_xor(pmax, 32));

        // T13 defer-max
        if (!__all(pmax <= mrow + 8.f)) {
            float mn = fmaxf(mrow, pmax);
            float s = __expf(mrow - mn);
            mrow = mn;
            lrow *= s;
            #pragma unroll
            for (int df = 0; df < 4; df++)
                #pragma unroll
                for (int r = 0; r < 4; r++) oT[df][r] *= s;
        }

        float psum = 0.f;
        #pragma unroll
        for (int kf = 0; kf < 4; kf++)
            #pragma unroll
            for (int r = 0; r < 4; r++) {
                float p = __expf(sc[kf][r] - mrow);
                sc[kf][r] = p;
                psum += p;
            }
        psum += __shfl_xor(psum, 16);
        psum += __shfl_xor(psum, 32);
        lrow += psum;

        // pack P to B-frags — lane-local thanks to the V permutation
        bf16x8 pb0, pb1;
        #pragma unroll
        for (int r = 0; r < 4; r++) {
            pb0[r]     = (bf16)sc[0][r];
            pb0[4 + r] = (bf16)sc[1][r];
            pb1[r]     = (bf16)sc[2][r];
            pb1[4 + r] = (bf16)sc[3][r];
        }

        // O^T += V^T · P^T: A = permuted V^T frag, B = packed P regs
        #pragma unroll
        for (int df = 0; df < 4; df++) {
            bf16x8 av0 = *(const bf16x8*)&vt_lds[(df * 16 + lr) * 72 + lh * 8];
            bf16x8 av1 = *(const bf16x8*)&vt_lds[(df * 16 + lr) * 72 + 32 + lh * 8];
            oT[df] = MFMA16(av0, pb0, oT[df]);
            oT[df] = MFMA16(av1, pb1, oT[df]);
        }
        __syncthreads();
    }

    float inv = 1.f / lrow;
    int orow = q0 + w * 16 + lr;
    #pragma unroll
    for (int df = 0; df < 4; df++) {
        bf16x4 o4;
        #pragma unroll
        for (int r = 0; r < 4; r++) o4[r] = (bf16)(oT[df][r] * inv);
        *(bf16x4*)&ctx[((size_t)b * S_ + orow) * D_ + h * 64 + df * 16 + lh * 4] = o4;
    }
}

extern "C" void kernel_launch(void* const* d_in, const int* in_sizes, int n_in,
                              void* d_out, int out_size, void* d_ws, size_t ws_size,
                              hipStream_t stream) {
    const float* x  = (const float*)d_in[0];
    const float* Wq = (const float*)d_in[1];
    const float* bq = (const float*)d_in[2];
    const float* Wk = (const float*)d_in[3];
    const float* bk = (const float*)d_in[4];
    const float* Wv = (const float*)d_in[5];
    const float* bv = (const float*)d_in[6];
    const float* Wo = (const float*)d_in[7];
    const float* bo = (const float*)d_in[8];
    const float* W1 = (const float*)d_in[9];
    const float* b1 = (const float*)d_in[10];
    const float* W2 = (const float*)d_in[11];
    const float* b2 = (const float*)d_in[12];
    const float* g1 = (const float*)d_in[13];
    const float* s1 = (const float*)d_in[14];
    const float* g2 = (const float*)d_in[15];
    const float* s2 = (const float*)d_in[16];
    float* out = (float*)d_out;

    char* ws = (char*)d_ws;
    size_t off = 0;
    auto alloc = [&](size_t bytes) -> char* {
        char* p = ws + off; off += (bytes + 255) & ~(size_t)255; return p;
    };
    bf16*  wt_qkv = (bf16*)alloc((size_t)QKVN * D_ * 2);
    bf16*  wt_o   = (bf16*)alloc((size_t)D_ * D_ * 2);
    bf16*  wt_1   = (bf16*)alloc((size_t)FF_ * D_ * 2);
    bf16*  wt_2   = (bf16*)alloc((size_t)D_ * FF_ * 2);
    float* qkvb   = (float*)alloc((size_t)QKVN * 4);
    bf16*  h1     = (bf16*)alloc((size_t)M_ * D_ * 2);
    bf16*  qkv    = (bf16*)alloc((size_t)M_ * QKVN * 2);
    bf16*  vtbuf  = (bf16*)alloc((size_t)M_ * D_ * 2);
    bf16*  ctx    = (bf16*)alloc((size_t)M_ * D_ * 2);
    float* x2     = (float*)alloc((size_t)M_ * D_ * 4);
    bf16*  h2     = (bf16*)alloc((size_t)M_ * D_ * 2);
    bf16*  gbuf   = (bf16*)alloc((size_t)M_ * FF_ * 2);
    float* part   = (float*)alloc((size_t)4 * M_ * D_ * 4);   // split-K partials (shared)

    // weight prep
    transpose_cast<<<dim3(16, 16), 256, 0, stream>>>(Wq, wt_qkv, D_, D_);
    transpose_cast<<<dim3(16, 16), 256, 0, stream>>>(Wk, wt_qkv + (size_t)D_ * D_, D_, D_);
    transpose_cast<<<dim3(16, 16), 256, 0, stream>>>(Wv, wt_qkv + (size_t)2 * D_ * D_, D_, D_);
    transpose_cast<<<dim3(16, 16), 256, 0, stream>>>(Wo, wt_o, D_, D_);
    transpose_cast<<<dim3(16, 64), 256, 0, stream>>>(W1, wt_1, D_, FF_);
    transpose_cast<<<dim3(64, 16), 256, 0, stream>>>(W2, wt_2, FF_, D_);
    concat3<<<12, 256, 0, stream>>>(bq, bk, bv, qkvb);

    // block
    ln_kernel<<<M_ / 4, 256, 0, stream>>>(x, g1, s1, h1);
    gemm256<0><<<dim3(QKVN / 256, M_ / 256, 1), 512, 0, stream>>>(h1, wt_qkv, qkvb, qkv, M_, QKVN, D_, D_);
    transpose_v<<<dim3(S_ / 64, B_ * H_), 256, 0, stream>>>(qkv, vtbuf);
    attn_kernel<<<dim3(B_ * H_, S_ / 64), 256, 0, stream>>>(qkv, vtbuf, ctx);
    gemm256<3><<<dim3(D_ / 256, M_ / 256, 4), 512, 0, stream>>>(ctx, wt_o, nullptr, part, M_, D_, D_, D_ / 4);
    reduce_ln<<<M_, 256, 0, stream>>>(part, bo, x, g2, s2, x2, h2);
    gemm256<2><<<dim3(FF_ / 256, M_ / 256, 1), 512, 0, stream>>>(h2, wt_1, b1, gbuf, M_, FF_, D_, D_);
    gemm256<3><<<dim3(D_ / 256, M_ / 256, 4), 512, 0, stream>>>(gbuf, wt_2, nullptr, part, M_, D_, FF_, FF_ / 4);
    reduce4<<<(M_ * D_) / 1024, 256, 0, stream>>>(part, b2, x2, out);
}

// Round 8
// 354.057 us; speedup vs baseline: 1.1977x; 1.0546x over previous
//
#include <hip/hip_runtime.h>
#include <hip/hip_bf16.h>
#include <math.h>

#define D_   1024
#define H_   16
#define HD_  64
#define S_   2048
#define B_   2
#define FF_  4096
#define M_   (B_*S_)      // 4096 rows
#define QKVN (3*D_)       // 3072

typedef __bf16 bf16;
typedef bf16 bf16x8 __attribute__((ext_vector_type(8)));
typedef bf16 bf16x4 __attribute__((ext_vector_type(4)));
typedef float f32x4 __attribute__((ext_vector_type(4)));

#define MFMA16(a,b,c) __builtin_amdgcn_mfma_f32_16x16x32_bf16(a,b,c,0,0,0)

// async global->LDS 16B per lane (wave-uniform LDS base + lane*16)
__device__ __forceinline__ void gld16(const void* g, void* l) {
    __builtin_amdgcn_global_load_lds(
        (const __attribute__((address_space(1))) void*)g,
        (__attribute__((address_space(3))) void*)l, 16, 0, 0);
}

// ------- fused weight prep: 6 transposes (f32 [K][N] -> bf16 [N][K]) + bias concat -------
// grid: 3072 transpose tiles (64x64) + 12 bias blocks.
__global__ __launch_bounds__(256) void prep_weights(
        const float* __restrict__ Wq, const float* __restrict__ Wk,
        const float* __restrict__ Wv, const float* __restrict__ Wo,
        const float* __restrict__ W1, const float* __restrict__ W2,
        const float* __restrict__ bq, const float* __restrict__ bk,
        const float* __restrict__ bv,
        bf16* __restrict__ wt_qkv, bf16* __restrict__ wt_o,
        bf16* __restrict__ wt_1, bf16* __restrict__ wt_2,
        float* __restrict__ qkvb) {
    int t = blockIdx.x;
    if (t >= 3072) {            // bias concat
        int i = (t - 3072) * 256 + threadIdx.x;
        qkvb[i] = (i < 1024) ? bq[i] : (i < 2048 ? bk[i - 1024] : bv[i - 2048]);
        return;
    }
    const float* W; bf16* WT; int K, N, rel;
    if (t < 1024) {             // Wq, Wk, Wv, Wo: 256 tiles each
        int wsel = t >> 8; rel = t & 255; K = 1024; N = 1024;
        W  = wsel == 0 ? Wq : wsel == 1 ? Wk : wsel == 2 ? Wv : Wo;
        WT = wsel == 3 ? wt_o : wt_qkv + (size_t)wsel * 1024 * 1024;
    } else if (t < 2048) { rel = t - 1024; W = W1; WT = wt_1; K = 1024; N = 4096; }
    else                 { rel = t - 2048; W = W2; WT = wt_2; K = 4096; N = 1024; }
    int ntx = N >> 6;
    int k0 = (rel / ntx) * 64, n0 = (rel % ntx) * 64;

    __shared__ float tl[64][65];
    int tid = threadIdx.x;
    int tr = tid >> 4, tc = tid & 15;
    #pragma unroll
    for (int i = 0; i < 4; i++) {
        int r = tr + i * 16;
        float4 v = *(const float4*)&W[(size_t)(k0 + r) * N + n0 + tc * 4];
        tl[r][tc * 4 + 0] = v.x; tl[r][tc * 4 + 1] = v.y;
        tl[r][tc * 4 + 2] = v.z; tl[r][tc * 4 + 3] = v.w;
    }
    __syncthreads();
    #pragma unroll
    for (int i = 0; i < 4; i++) {
        int r = tr + i * 16;
        bf16x4 o;
        #pragma unroll
        for (int j = 0; j < 4; j++) o[j] = (bf16)tl[tc * 4 + j][r];
        *(bf16x4*)&WT[(size_t)(n0 + r) * K + k0 + tc * 4] = o;
    }
}

// ---------------- transpose V section of qkv into VT[bh][d][s] ----------------
__global__ __launch_bounds__(256) void transpose_v(const bf16* __restrict__ qkv,
                                                   bf16* __restrict__ VT) {
    __shared__ __align__(16) bf16 t[64][72];
    int bh = blockIdx.y; int b = bh >> 4, h = bh & 15;
    int s0 = blockIdx.x * 64;
    const bf16* vbase = qkv + (size_t)b * S_ * QKVN + 2048 + h * 64;
    int tid = threadIdx.x;
    #pragma unroll
    for (int i = 0; i < 2; i++) {
        int e = tid + i * 256; int r = e >> 3, cg = e & 7;
        *(bf16x8*)&t[r][cg * 8] = *(const bf16x8*)&vbase[(size_t)(s0 + r) * QKVN + cg * 8];
    }
    __syncthreads();
    #pragma unroll
    for (int i = 0; i < 2; i++) {
        int e = tid + i * 256; int d = e >> 3, cg = e & 7;
        bf16x8 v;
        #pragma unroll
        for (int j = 0; j < 8; j++) v[j] = t[cg * 8 + j][d];
        *(bf16x8*)&VT[((size_t)bh * 64 + d) * S_ + s0 + cg * 8] = v;
    }
}

// ---------------- layernorm (ddof=1, eps on std) f32 in -> bf16 out ----------------
__global__ __launch_bounds__(256) void ln_kernel(const float* __restrict__ x,
                                                 const float* __restrict__ g,
                                                 const float* __restrict__ sh,
                                                 bf16* __restrict__ out) {
    int row = blockIdx.x * 4 + (threadIdx.x >> 6);
    int lane = threadIdx.x & 63;
    const float4* xr = (const float4*)(x + (size_t)row * D_);
    float4 v[4]; float sum = 0.f, ss = 0.f;
    #pragma unroll
    for (int c = 0; c < 4; c++) {
        v[c] = xr[lane + 64 * c];
        sum += v[c].x + v[c].y + v[c].z + v[c].w;
        ss  += v[c].x * v[c].x + v[c].y * v[c].y + v[c].z * v[c].z + v[c].w * v[c].w;
    }
    #pragma unroll
    for (int o = 32; o; o >>= 1) { sum += __shfl_xor(sum, o); ss += __shfl_xor(ss, o); }
    float mean = sum * (1.f / 1024.f);
    float var  = (ss - 1024.f * mean * mean) * (1.f / 1023.f);
    float inv  = 1.f / (sqrtf(var) + 1e-5f);
    const float4* gp = (const float4*)g;
    const float4* sp = (const float4*)sh;
    bf16x4* op = (bf16x4*)(out + (size_t)row * D_);
    #pragma unroll
    for (int c = 0; c < 4; c++) {
        int idx = lane + 64 * c;
        float4 gv = gp[idx], sv = sp[idx];
        float y0 = (v[c].x - mean) * inv * gv.x + sv.x;
        float y1 = (v[c].y - mean) * inv * gv.y + sv.y;
        float y2 = (v[c].z - mean) * inv * gv.z + sv.z;
        float y3 = (v[c].w - mean) * inv * gv.w + sv.w;
        op[idx] = (bf16x4){(bf16)y0, (bf16)y1, (bf16)y2, (bf16)y3};
    }
}

// ======== 256x256 BK=32 8-wave GEMM, 4-buffer ring + 2-phase/K-step interleave ========
// Phase A: {vmcnt(4) [tile kt landed]; ds_read B n0-3 + A m0-3; stage half1 of kt+2;
//           barrier; setprio; 16 MFMA (m0-3 x n0-3); setprio}
// Phase B: {ds_read A m4-7; stage half2 of kt+2; barrier; setprio; 16 MFMA; setprio}
// Race-safety: buffer (kt+2)&3's last reader is K-step kt-2 phase B, whose ds_reads are
// drained (compiler lgkm before its MFMA) before any wave passes the kt-1 phase-A barrier;
// the kt+2 stage issues only after the kt phase-A barrier -> >=3 barriers of separation.
// RAW: vmcnt(4) at phase A head guarantees tile kt's 4 loads landed (kt+1's in flight);
// final tile uses vmcnt(0).
// MODE 0: +bias -> bf16.  MODE 2: +bias, exact GELU -> bf16.  MODE 3: raw f32 split-K partial.
template<int MODE>
__global__ __launch_bounds__(512, 2) void gemm256(const bf16* __restrict__ A,
                                                  const bf16* __restrict__ BT,
                                                  const float* __restrict__ bias,
                                                  void* __restrict__ outp,
                                                  int M, int N, int K, int KSLICE) {
    __shared__ __align__(16) bf16 a_lds[4 * 8192];
    __shared__ __align__(16) bf16 b_lds[4 * 8192];
    int tid = threadIdx.x, w = tid >> 6, lane = tid & 63;
    // XCD-chunked bijective swizzle over the whole grid (all grids here are %8==0)
    int gx = gridDim.x, gxy = gx * gridDim.y;
    int nwg = gxy * gridDim.z;
    int flat = blockIdx.z * gxy + blockIdx.y * gx + blockIdx.x;
    int chunk = nwg >> 3;
    int swz = (flat & 7) * chunk + (flat >> 3);
    int z = swz / gxy, rem = swz - z * gxy;
    int m0 = (rem / gx) * 256, n0 = (rem % gx) * 256;
    int kbase = z * KSLICE;
    int nk = KSLICE >> 5;
    int lr = lane & 15, lh = lane >> 4;
    int wr = w >> 2, wc = w & 3;

    // staging granules: g = w*64 + lane (+512). row = g>>2, lds chunk = g&3,
    // global chunk = (g&3) ^ ((row>>1)&3)  [T2 source-side swizzle; LDS dest linear]
    int g0 = w * 64 + lane;
    int row0 = g0 >> 2, cs0 = (g0 & 3) ^ ((row0 >> 1) & 3);
    int g1 = g0 + 512;
    int row1 = g1 >> 2, cs1 = (g1 & 3) ^ ((row1 >> 1) & 3);
    int dst0 = w * 512;
    int dst1 = w * 512 + 4096;

    auto STAGE_H1 = [&](int buf, int k0) {   // rows 0-127 of A and B
        gld16(&A [(size_t)(m0 + row0) * K + k0 + cs0 * 8], a_lds + buf * 8192 + dst0);
        gld16(&BT[(size_t)(n0 + row0) * K + k0 + cs0 * 8], b_lds + buf * 8192 + dst0);
    };
    auto STAGE_H2 = [&](int buf, int k0) {   // rows 128-255 of A and B
        gld16(&A [(size_t)(m0 + row1) * K + k0 + cs1 * 8], a_lds + buf * 8192 + dst1);
        gld16(&BT[(size_t)(n0 + row1) * K + k0 + cs1 * 8], b_lds + buf * 8192 + dst1);
    };

    f32x4 acc[8][4] = {};
    STAGE_H1(0, kbase); STAGE_H2(0, kbase);
    STAGE_H1(1, kbase + 32); STAGE_H2(1, kbase + 32);
    asm volatile("s_waitcnt vmcnt(4)" ::: "memory");   // tile 0 landed
    __builtin_amdgcn_s_barrier();

    int rchk = (lr >> 1) & 3;
    int fcol = ((lh ^ rchk) * 8);
    for (int kt = 0; kt < nk; ++kt) {
        const bf16* ab = a_lds + (kt & 3) * 8192;
        const bf16* bb = b_lds + (kt & 3) * 8192;
        // ---------------- phase A ----------------
        if (kt + 1 < nk) asm volatile("s_waitcnt vmcnt(4)" ::: "memory");
        else             asm volatile("s_waitcnt vmcnt(0)" ::: "memory");
        __builtin_amdgcn_sched_barrier(0);
        bf16x8 bf[4], af[4];
        #pragma unroll
        for (int n = 0; n < 4; n++)
            bf[n] = *(const bf16x8*)&bb[(wc * 64 + n * 16 + lr) * 32 + fcol];
        #pragma unroll
        for (int m = 0; m < 4; m++)
            af[m] = *(const bf16x8*)&ab[(wr * 128 + m * 16 + lr) * 32 + fcol];
        if (kt + 2 < nk) STAGE_H1((kt + 2) & 3, kbase + (kt + 2) * 32);
        __builtin_amdgcn_sched_barrier(0);
        __builtin_amdgcn_s_barrier();
        __builtin_amdgcn_s_setprio(1);
        #pragma unroll
        for (int m = 0; m < 4; m++)
            #pragma unroll
            for (int n = 0; n < 4; n++)
                acc[m][n] = MFMA16(af[m], bf[n], acc[m][n]);
        __builtin_amdgcn_s_setprio(0);
        // ---------------- phase B ----------------
        bf16x8 ah[4];
        #pragma unroll
        for (int m = 0; m < 4; m++)
            ah[m] = *(const bf16x8*)&ab[(wr * 128 + (m + 4) * 16 + lr) * 32 + fcol];
        if (kt + 2 < nk) STAGE_H2((kt + 2) & 3, kbase + (kt + 2) * 32);
        __builtin_amdgcn_sched_barrier(0);
        __builtin_amdgcn_s_barrier();
        __builtin_amdgcn_s_setprio(1);
        #pragma unroll
        for (int m = 0; m < 4; m++)
            #pragma unroll
            for (int n = 0; n < 4; n++)
                acc[m + 4][n] = MFMA16(ah[m], bf[n], acc[m + 4][n]);
        __builtin_amdgcn_s_setprio(0);
    }

    // epilogue
    #pragma unroll
    for (int m = 0; m < 8; m++) {
        #pragma unroll
        for (int n = 0; n < 4; n++) {
            int col = n0 + wc * 64 + n * 16 + lr;
            float bv = (MODE == 3) ? 0.f : bias[col];
            #pragma unroll
            for (int r = 0; r < 4; r++) {
                int row = m0 + wr * 128 + m * 16 + lh * 4 + r;
                float vv = acc[m][n][r] + bv;
                if (MODE == 2) vv = 0.5f * vv * (1.f + erff(vv * 0.70710678118654752f));
                if (MODE == 3) ((float*)outp)[((size_t)z * M + row) * N + col] = vv;
                else           ((bf16*)outp)[(size_t)row * N + col] = (bf16)vv;
            }
        }
    }
}

// ---------------- split-K reduce: out = sum_z part[z] + bias + res (f32, N=1024) ----------------
__global__ __launch_bounds__(256) void reduce4(const float* __restrict__ part,
                                               const float* __restrict__ bias,
                                               const float* __restrict__ res,
                                               float* __restrict__ out) {
    int i = blockIdx.x * 256 + threadIdx.x;
    const float4* p = (const float4*)part;
    const size_t s4 = (size_t)M_ * 1024 / 4;
    float4 a = p[i], b = p[i + s4], c = p[i + 2 * s4], d = p[i + 3 * s4];
    float4 bv = ((const float4*)bias)[i & 255];
    float4 rv = ((const float4*)res)[i];
    float4 o;
    o.x = a.x + b.x + c.x + d.x + bv.x + rv.x;
    o.y = a.y + b.y + c.y + d.y + bv.y + rv.y;
    o.z = a.z + b.z + c.z + d.z + bv.z + rv.z;
    o.w = a.w + b.w + c.w + d.w + bv.w + rv.w;
    ((float4*)out)[i] = o;
}

// ------- fused split-K reduce + LayerNorm: x2 = sum_z part + bias + res; h2 = LN(x2) -------
__global__ __launch_bounds__(256) void reduce_ln(const float* __restrict__ part,
                                                 const float* __restrict__ bias,
                                                 const float* __restrict__ res,
                                                 const float* __restrict__ g,
                                                 const float* __restrict__ sh,
                                                 float* __restrict__ x2,
                                                 bf16* __restrict__ h2) {
    __shared__ float s_sum[4], s_ss[4];
    int row = blockIdx.x, t = threadIdx.x;
    int wv = t >> 6, lane = t & 63;
    size_t i = (size_t)row * 256 + t;
    const float4* p = (const float4*)part;
    const size_t s4 = (size_t)M_ * 1024 / 4;
    float4 a = p[i], b = p[i + s4], c = p[i + 2 * s4], d = p[i + 3 * s4];
    float4 bv = ((const float4*)bias)[t];
    float4 rv = ((const float4*)res)[i];
    float4 v;
    v.x = a.x + b.x + c.x + d.x + bv.x + rv.x;
    v.y = a.y + b.y + c.y + d.y + bv.y + rv.y;
    v.z = a.z + b.z + c.z + d.z + bv.z + rv.z;
    v.w = a.w + b.w + c.w + d.w + bv.w + rv.w;
    ((float4*)x2)[i] = v;
    float sum = v.x + v.y + v.z + v.w;
    float ss  = v.x * v.x + v.y * v.y + v.z * v.z + v.w * v.w;
    #pragma unroll
    for (int o = 32; o; o >>= 1) { sum += __shfl_xor(sum, o); ss += __shfl_xor(ss, o); }
    if (lane == 0) { s_sum[wv] = sum; s_ss[wv] = ss; }
    __syncthreads();
    sum = s_sum[0] + s_sum[1] + s_sum[2] + s_sum[3];
    ss  = s_ss[0] + s_ss[1] + s_ss[2] + s_ss[3];
    float mean = sum * (1.f / 1024.f);
    float var  = (ss - 1024.f * mean * mean) * (1.f / 1023.f);
    float inv  = 1.f / (sqrtf(var) + 1e-5f);
    float4 gv = ((const float4*)g)[t], sv = ((const float4*)sh)[t];
    bf16x4 o4;
    o4[0] = (bf16)((v.x - mean) * inv * gv.x + sv.x);
    o4[1] = (bf16)((v.y - mean) * inv * gv.y + sv.y);
    o4[2] = (bf16)((v.z - mean) * inv * gv.z + sv.z);
    o4[3] = (bf16)((v.w - mean) * inv * gv.w + sv.w);
    *(bf16x4*)&h2[(size_t)row * D_ + t * 4] = o4;
}

// ---------------- causal flash attention v5 (unchanged from round 7) ----------------
__global__ __launch_bounds__(256) void attn_kernel(const bf16* __restrict__ qkv,
                                                   const bf16* __restrict__ VT,
                                                   bf16* __restrict__ ctx) {
    __shared__ __align__(16) bf16 k_lds[64 * 72];
    __shared__ __align__(16) bf16 vt_lds[64 * 72];
    int bh = blockIdx.x; int b = bh >> 4, h = bh & 15;
    int qt = gridDim.y - 1 - blockIdx.y;   // heavy-first
    int q0 = qt * 64;
    int tid = threadIdx.x, w = tid >> 6, lane = tid & 63;
    int lr = lane & 15, lh = lane >> 4;
    const size_t RS = QKVN;
    const bf16* qbase = qkv + (size_t)b * S_ * RS + h * 64;
    const bf16* kbase = qbase + 1024;
    const bf16* vtb = VT + (size_t)bh * 64 * S_;

    int qrow = q0 + w * 16 + lr;
    bf16x8 aq[2];
    #pragma unroll
    for (int dc = 0; dc < 2; dc++) {
        bf16x8 t8 = *(const bf16x8*)&qbase[(size_t)qrow * RS + dc * 32 + lh * 8];
        #pragma unroll
        for (int j = 0; j < 8; j++) t8[j] = (bf16)((float)t8[j] * 0.125f);
        aq[dc] = t8;
    }

    f32x4 oT[4] = {};
    float mrow = -1e30f, lrow = 0.f;

    int er = tid >> 3, ecg = tid & 7;
    int o0 = ecg * 2, o1 = o0 + 1;
    int p0 = (o0 & 8) + 2 * (o0 & 3) + ((o0 >> 2) & 1);
    int p1 = (o1 & 8) + 2 * (o1 & 3) + ((o1 >> 2) & 1);

    int ntile = qt + 1;
    bf16x8 kreg0 = *(const bf16x8*)&kbase[(size_t)er * RS + ecg * 8];
    bf16x8 kreg1 = *(const bf16x8*)&kbase[(size_t)(er + 32) * RS + ecg * 8];
    bf16x8 vreg0 = *(const bf16x8*)&vtb[(size_t)er * S_ + ecg * 8];
    bf16x8 vreg1 = *(const bf16x8*)&vtb[(size_t)(er + 32) * S_ + ecg * 8];

    for (int t = 0; t < ntile; t++) {
        int kv0 = t * 64;
        *(bf16x8*)&k_lds[er * 72 + ecg * 8]        = kreg0;
        *(bf16x8*)&k_lds[(er + 32) * 72 + ecg * 8] = kreg1;
        {
            bf16x4 lo0 = {vreg0[0], vreg0[1], vreg0[2], vreg0[3]};
            bf16x4 hi0 = {vreg0[4], vreg0[5], vreg0[6], vreg0[7]};
            bf16x4 lo1 = {vreg1[0], vreg1[1], vreg1[2], vreg1[3]};
            bf16x4 hi1 = {vreg1[4], vreg1[5], vreg1[6], vreg1[7]};
            *(bf16x4*)&vt_lds[er * 72 + p0 * 4]        = lo0;
            *(bf16x4*)&vt_lds[er * 72 + p1 * 4]        = hi0;
            *(bf16x4*)&vt_lds[(er + 32) * 72 + p0 * 4] = lo1;
            *(bf16x4*)&vt_lds[(er + 32) * 72 + p1 * 4] = hi1;
        }
        __syncthreads();
        if (t + 1 < ntile) {
            int kn = kv0 + 64;
            kreg0 = *(const bf16x8*)&kbase[(size_t)(kn + er) * RS + ecg * 8];
            kreg1 = *(const bf16x8*)&kbase[(size_t)(kn + er + 32) * RS + ecg * 8];
            vreg0 = *(const bf16x8*)&vtb[(size_t)er * S_ + kn + ecg * 8];
            vreg1 = *(const bf16x8*)&vtb[(size_t)(er + 32) * S_ + kn + ecg * 8];
        }

        f32x4 sc[4] = {};
        #pragma unroll
        for (int kf = 0; kf < 4; kf++)
            #pragma unroll
            for (int dc = 0; dc < 2; dc++) {
                bf16x8 ak = *(const bf16x8*)&k_lds[(kf * 16 + lr) * 72 + dc * 32 + lh * 8];
                sc[kf] = MFMA16(ak, aq[dc], sc[kf]);
            }

        if (t == ntile - 1) {
            int qg = q0 + w * 16 + lr;
            #pragma unroll
            for (int kf = 0; kf < 4; kf++)
                #pragma unroll
                for (int r = 0; r < 4; r++) {
                    int kvg = kv0 + kf * 16 + lh * 4 + r;
                    if (kvg > qg) sc[kf][r] = -100000.0f;
                }
        }

        float pmax = sc[0][0];
        #pragma unroll
        for (int kf = 0; kf < 4; kf++)
            #pragma unroll
            for (int r = 0; r < 4; r++) pmax = fmaxf(pmax, sc[kf][r]);
        pmax = fmaxf(pmax, __shfl_xor(pmax, 16));
        pmax = fmaxf(pmax, __shfl_xor(pmax, 32));

        if (!__all(pmax <= mrow + 8.f)) {
            float mn = fmaxf(mrow, pmax);
            float s = __expf(mrow - mn);
            mrow = mn;
            lrow *= s;
            #pragma unroll
            for (int df = 0; df < 4; df++)
                #pragma unroll
                for (int r = 0; r < 4; r++) oT[df][r] *= s;
        }

        float psum = 0.f;
        #pragma unroll
        for (int kf = 0; kf < 4; kf++)
            #pragma unroll
            for (int r = 0; r < 4; r++) {
                float p = __expf(sc[kf][r] - mrow);
                sc[kf][r] = p;
                psum += p;
            }
        psum += __shfl_xor(psum, 16);
        psum += __shfl_xor(psum, 32);
        lrow += psum;

        bf16x8 pb0, pb1;
        #pragma unroll
        for (int r = 0; r < 4; r++) {
            pb0[r]     = (bf16)sc[0][r];
            pb0[4 + r] = (bf16)sc[1][r];
            pb1[r]     = (bf16)sc[2][r];
            pb1[4 + r] = (bf16)sc[3][r];
        }

        #pragma unroll
        for (int df = 0; df < 4; df++) {
            bf16x8 av0 = *(const bf16x8*)&vt_lds[(df * 16 + lr) * 72 + lh * 8];
            bf16x8 av1 = *(const bf16x8*)&vt_lds[(df * 16 + lr) * 72 + 32 + lh * 8];
            oT[df] = MFMA16(av0, pb0, oT[df]);
            oT[df] = MFMA16(av1, pb1, oT[df]);
        }
        __syncthreads();
    }

    float inv = 1.f / lrow;
    int orow = q0 + w * 16 + lr;
    #pragma unroll
    for (int df = 0; df < 4; df++) {
        bf16x4 o4;
        #pragma unroll
        for (int r = 0; r < 4; r++) o4[r] = (bf16)(oT[df][r] * inv);
        *(bf16x4*)&ctx[((size_t)b * S_ + orow) * D_ + h * 64 + df * 16 + lh * 4] = o4;
    }
}

extern "C" void kernel_launch(void* const* d_in, const int* in_sizes, int n_in,
                              void* d_out, int out_size, void* d_ws, size_t ws_size,
                              hipStream_t stream) {
    const float* x  = (const float*)d_in[0];
    const float* Wq = (const float*)d_in[1];
    const float* bq = (const float*)d_in[2];
    const float* Wk = (const float*)d_in[3];
    const float* bk = (const float*)d_in[4];
    const float* Wv = (const float*)d_in[5];
    const float* bv = (const float*)d_in[6];
    const float* Wo = (const float*)d_in[7];
    const float* bo = (const float*)d_in[8];
    const float* W1 = (const float*)d_in[9];
    const float* b1 = (const float*)d_in[10];
    const float* W2 = (const float*)d_in[11];
    const float* b2 = (const float*)d_in[12];
    const float* g1 = (const float*)d_in[13];
    const float* s1 = (const float*)d_in[14];
    const float* g2 = (const float*)d_in[15];
    const float* s2 = (const float*)d_in[16];
    float* out = (float*)d_out;

    char* ws = (char*)d_ws;
    size_t off = 0;
    auto alloc = [&](size_t bytes) -> char* {
        char* p = ws + off; off += (bytes + 255) & ~(size_t)255; return p;
    };
    bf16*  wt_qkv = (bf16*)alloc((size_t)QKVN * D_ * 2);
    bf16*  wt_o   = (bf16*)alloc((size_t)D_ * D_ * 2);
    bf16*  wt_1   = (bf16*)alloc((size_t)FF_ * D_ * 2);
    bf16*  wt_2   = (bf16*)alloc((size_t)D_ * FF_ * 2);
    float* qkvb   = (float*)alloc((size_t)QKVN * 4);
    bf16*  h1     = (bf16*)alloc((size_t)M_ * D_ * 2);
    bf16*  qkv    = (bf16*)alloc((size_t)M_ * QKVN * 2);
    bf16*  vtbuf  = (bf16*)alloc((size_t)M_ * D_ * 2);
    bf16*  ctx    = (bf16*)alloc((size_t)M_ * D_ * 2);
    float* x2     = (float*)alloc((size_t)M_ * D_ * 4);
    bf16*  h2     = (bf16*)alloc((size_t)M_ * D_ * 2);
    bf16*  gbuf   = (bf16*)alloc((size_t)M_ * FF_ * 2);
    float* part   = (float*)alloc((size_t)4 * M_ * D_ * 4);   // split-K partials (shared)

    // weight prep (single launch)
    prep_weights<<<3084, 256, 0, stream>>>(Wq, Wk, Wv, Wo, W1, W2, bq, bk, bv,
                                           wt_qkv, wt_o, wt_1, wt_2, qkvb);

    // block
    ln_kernel<<<M_ / 4, 256, 0, stream>>>(x, g1, s1, h1);
    gemm256<0><<<dim3(QKVN / 256, M_ / 256, 1), 512, 0, stream>>>(h1, wt_qkv, qkvb, qkv, M_, QKVN, D_, D_);
    transpose_v<<<dim3(S_ / 64, B_ * H_), 256, 0, stream>>>(qkv, vtbuf);
    attn_kernel<<<dim3(B_ * H_, S_ / 64), 256, 0, stream>>>(qkv, vtbuf, ctx);
    gemm256<3><<<dim3(D_ / 256, M_ / 256, 4), 512, 0, stream>>>(ctx, wt_o, nullptr, part, M_, D_, D_, D_ / 4);
    reduce_ln<<<M_, 256, 0, stream>>>(part, bo, x, g2, s2, x2, h2);
    gemm256<2><<<dim3(FF_ / 256, M_ / 256, 1), 512, 0, stream>>>(h2, wt_1, b1, gbuf, M_, FF_, D_, D_);
    gemm256<3><<<dim3(D_ / 256, M_ / 256, 4), 512, 0, stream>>>(gbuf, wt_2, nullptr, part, M_, D_, FF_, FF_ / 4);
    reduce4<<<(M_ * D_) / 1024, 256, 0, stream>>>(part, b2, x2, out);
}